// Round 1
// 799.772 us; speedup vs baseline: 1.3402x; 1.3402x over previous
//
#include <hip/hip_runtime.h>

// Problem constants
#define BQ   16
#define CCH  256
#define HWP  4096   // H*W

typedef unsigned short u16;
typedef unsigned int   u32;
typedef __attribute__((ext_vector_type(8))) short bf16x8;   // 8 bf16 (4 VGPRs)
typedef __attribute__((ext_vector_type(4))) float f32x4;    // MFMA C/D

__device__ __forceinline__ float bf2f(u16 h) {
    union { u32 u; float f; } v; v.u = (u32)h << 16; return v.f;
}
__device__ __forceinline__ u16 f2bf_bits(float f) {
    u32 u = __float_as_uint(f);
    u32 r = (u + 0x7fffu + ((u >> 16) & 1u)) >> 16;   // RNE
    return (u16)r;
}
__device__ __forceinline__ u32 pack2(float a, float b) {
    return (u32)f2bf_bits(a) | ((u32)f2bf_bits(b) << 16);
}

// ---------------------------------------------------------------------------
// fp32 -> bf16 weight convert. n4 = count/4.
// ---------------------------------------------------------------------------
__global__ __launch_bounds__(256) void f2bf_kernel(
    const float* __restrict__ src, u16* __restrict__ dst, int n4)
{
    int i = blockIdx.x * 256 + threadIdx.x;
    if (i < n4) {
        float4 v = ((const float4*)src)[i];
        uint2 p; p.x = pack2(v.x, v.y); p.y = pack2(v.z, v.w);
        ((uint2*)dst)[i] = p;
    }
}

// ---------------------------------------------------------------------------
// LayerNorm over C + transpose: x fp32 [b][c][n] -> outT bf16 [b][n][c].
// v2: LDS-staged tile, 32 n x 256 c per block, 8 threads cooperate per n.
//   phase 1: lanes read 128B-contiguous n-runs per channel, stage f32 tile
//            in LDS (row stride 257 -> conflict-free writes), partial sums
//            reduced via LDS.
//   phase 2: lanes map to consecutive c-chunks -> 1KB contiguous per wave
//            store (fixes 52MB->32MB write amplification).
// grid (128, 16), block 256.  LDS ~37 KB -> 4 blocks/CU, 16 waves/CU.
// ---------------------------------------------------------------------------
__global__ __launch_bounds__(256) void ln_t_f32(
    const float* __restrict__ x, const float* __restrict__ wgt,
    const float* __restrict__ bias, u16* __restrict__ outT)
{
    __shared__ float tile[32 * 257];   // [n][c], stride 257 floats
    __shared__ float ps[256], pss[256];
    __shared__ float smu[32], srs[32];
    __shared__ float sw[CCH], sb[CCH];
    int tid = threadIdx.x;
    sw[tid] = wgt[tid]; sb[tid] = bias[tid];

    int nl = tid & 31, cg = tid >> 5;        // n-lane, channel group
    int b  = blockIdx.y;
    int n0 = blockIdx.x * 32;
    const float* xp = x + (size_t)b * CCH * HWP + n0 + nl;

    float s = 0.f, ss = 0.f;
    #pragma unroll
    for (int j = 0; j < 32; ++j) {
        int c = cg * 32 + j;
        float v = xp[(size_t)c * HWP];
        tile[nl * 257 + c] = v;
        s += v; ss += v * v;
    }
    ps[tid] = s; pss[tid] = ss;
    __syncthreads();

    if (tid < 32) {
        float t = 0.f, tt = 0.f;
        #pragma unroll
        for (int g = 0; g < 8; ++g) { t += ps[g * 32 + tid]; tt += pss[g * 32 + tid]; }
        float u = t * (1.0f / CCH);
        smu[tid] = u;
        srs[tid] = rsqrtf(tt * (1.0f / CCH) - u * u + 1e-6f);
    }
    __syncthreads();

    int c0 = (tid & 31) * 8, nb = tid >> 5;  // lanes 0..31 -> consecutive c
    #pragma unroll
    for (int r = 0; r < 4; ++r) {
        int n = r * 8 + nb;
        float u = smu[n], rr = srs[n];
        u16 tmp[8];
        #pragma unroll
        for (int j = 0; j < 8; ++j) {
            float v = tile[n * 257 + c0 + j];
            tmp[j] = f2bf_bits(sw[c0 + j] * (v - u) * rr + sb[c0 + j]);
        }
        *(uint4*)(outT + ((size_t)b * HWP + n0 + n) * CCH + c0) = *(uint4*)tmp;
    }
}

// ---------------------------------------------------------------------------
// Same, but input already bf16 T-layout [b][n][c] (used for LN of x).
// v2: 4 threads cooperate per row (64 c each, kept in registers),
// quad shuffle-reduce for stats. grid 1024 -> 16 waves/CU.
// ---------------------------------------------------------------------------
__global__ __launch_bounds__(256) void ln_t_bf16T(
    const u16* __restrict__ xT, const float* __restrict__ wgt,
    const float* __restrict__ bias, u16* __restrict__ outT)
{
    __shared__ float sw[CCH], sb[CCH];
    int tid = threadIdx.x;
    sw[tid] = wgt[tid]; sb[tid] = bias[tid];
    __syncthreads();
    int gid = blockIdx.x * 256 + tid;
    int ng = gid >> 2, q = gid & 3;          // 4 threads per (b,n) row
    int b = ng >> 12, n = ng & 4095;
    const u16* xp = xT + ((size_t)b * HWP + n) * CCH + q * 64;
    uint4 w4[8];
    float s = 0.f, ss = 0.f;
    #pragma unroll
    for (int k = 0; k < 8; ++k) {
        w4[k] = *(const uint4*)(xp + k * 8);
        const u16* ph = (const u16*)&w4[k];
        #pragma unroll
        for (int j = 0; j < 8; ++j) { float v = bf2f(ph[j]); s += v; ss += v * v; }
    }
    s  += __shfl_xor(s, 1);  s  += __shfl_xor(s, 2);
    ss += __shfl_xor(ss, 1); ss += __shfl_xor(ss, 2);
    float u = s * (1.0f / CCH);
    float r = rsqrtf(ss * (1.0f / CCH) - u * u + 1e-6f);
    u16* op = outT + ((size_t)b * HWP + n) * CCH + q * 64;
    #pragma unroll
    for (int k = 0; k < 8; ++k) {
        const u16* ph = (const u16*)&w4[k];
        int cb = q * 64 + k * 8;
        u16 tmp[8];
        #pragma unroll
        for (int j = 0; j < 8; ++j)
            tmp[j] = f2bf_bits(sw[cb + j] * (bf2f(ph[j]) - u) * r + sb[cb + j]);
        *(uint4*)(op + k * 8) = *(uint4*)tmp;
    }
}

// ---------------------------------------------------------------------------
// MFMA GEMM: Out[b][m][n] = sum_k Wb[m][k] * XT[b][n][k]   (K=256)
// 128x128 block tile, 4 waves (2x2), each wave 64x64 = 4x4 MFMA 16x16x32.
// MODE 0: orig bf16 out                      (q, fc1)
// MODE 1: m<256 -> orig bf16 K; m>=256 -> T bf16 V        (kv)
// MODE 2: +bias +resF(img); fp32 orig outF (d_out) AND T bf16 outB (xT)
// MODE 3: +resF; fp32 orig outF (d_out)     (fc2)
// grid: (32, M/128, 16)
// ---------------------------------------------------------------------------
template<int MODE>
__global__ __launch_bounds__(256) void gemmT(
    const u16* __restrict__ Wb, const u16* __restrict__ XT,
    u16* __restrict__ outA, u16* __restrict__ outB,
    float* __restrict__ outF, const float* __restrict__ bias,
    const float* __restrict__ resF)
{
    int tid = threadIdx.x;
    int w = tid >> 6, lane = tid & 63;
    int lr = lane & 15, quad = lane >> 4;
    int wm = w >> 1, wn = w & 1;
    int b  = blockIdx.z;
    int m0 = blockIdx.y * 128 + wm * 64;
    int n0 = blockIdx.x * 128 + wn * 64;

    f32x4 zz = {0.f, 0.f, 0.f, 0.f};
    f32x4 acc[4][4];
    #pragma unroll
    for (int i = 0; i < 4; ++i)
        #pragma unroll
        for (int j = 0; j < 4; ++j) acc[i][j] = zz;

    const u16* Ab = Wb + (size_t)(m0 + lr) * CCH + quad * 8;
    const u16* Bb = XT + ((size_t)b * HWP + n0 + lr) * CCH + quad * 8;

    #pragma unroll
    for (int k0 = 0; k0 < 256; k0 += 32) {
        bf16x8 a[4], bb[4];
        #pragma unroll
        for (int mi = 0; mi < 4; ++mi) a[mi]  = *(const bf16x8*)(Ab + (size_t)mi * 16 * CCH + k0);
        #pragma unroll
        for (int nj = 0; nj < 4; ++nj) bb[nj] = *(const bf16x8*)(Bb + (size_t)nj * 16 * CCH + k0);
        #pragma unroll
        for (int mi = 0; mi < 4; ++mi)
            #pragma unroll
            for (int nj = 0; nj < 4; ++nj)
                acc[mi][nj] = __builtin_amdgcn_mfma_f32_16x16x32_bf16(a[mi], bb[nj], acc[mi][nj], 0, 0, 0);
    }

    #pragma unroll
    for (int mi = 0; mi < 4; ++mi) {
        int mbase = m0 + mi * 16 + quad * 4;   // 4 consecutive m via reg idx
        #pragma unroll
        for (int nj = 0; nj < 4; ++nj) {
            int n = n0 + nj * 16 + lr;
            if (MODE == 0 || (MODE == 1 && m0 < 256)) {
                size_t base = ((size_t)b * CCH + mbase) * HWP + n;
                #pragma unroll
                for (int r = 0; r < 4; ++r)
                    outA[base + (size_t)r * HWP] = f2bf_bits(acc[mi][nj][r]);
            } else if (MODE == 1) {            // V-half -> T layout
                uint2 p;
                p.x = pack2(acc[mi][nj][0], acc[mi][nj][1]);
                p.y = pack2(acc[mi][nj][2], acc[mi][nj][3]);
                *(uint2*)(outB + ((size_t)b * HWP + n) * CCH + (mbase - 256)) = p;
            } else if (MODE == 2) {
                float v[4];
                size_t rb = ((size_t)b * CCH + mbase) * HWP + n;
                #pragma unroll
                for (int r = 0; r < 4; ++r) {
                    v[r] = acc[mi][nj][r] + bias[mbase + r] + resF[rb + (size_t)r * HWP];
                    outF[rb + (size_t)r * HWP] = v[r];
                }
                uint2 p; p.x = pack2(v[0], v[1]); p.y = pack2(v[2], v[3]);
                *(uint2*)(outB + ((size_t)b * HWP + n) * CCH + mbase) = p;
            } else {                           // MODE 3
                size_t rb = ((size_t)b * CCH + mbase) * HWP + n;
                #pragma unroll
                for (int r = 0; r < 4; ++r)
                    outF[rb + (size_t)r * HWP] = acc[mi][nj][r] + resF[rb + (size_t)r * HWP];
            }
        }
    }
}

// ---------------------------------------------------------------------------
// Reciprocal L2 row norms over HW (vectorized uint4 loads).
// grid: 3*B*C blocks, block 256.
// ---------------------------------------------------------------------------
__global__ __launch_bounds__(256) void rownorm_kernel(
    const u16* __restrict__ q, const u16* __restrict__ Ktex, const u16* __restrict__ Kdep,
    float* __restrict__ rq, float* __restrict__ rkt, float* __restrict__ rkd)
{
    int tid = threadIdx.x;
    int idx = blockIdx.x;
    int which = idx >> 12;
    int bc = idx & 4095;
    const u16* row = (which == 0 ? q : which == 1 ? Ktex : Kdep) + (size_t)bc * HWP;
    float* out = (which == 0 ? rq : which == 1 ? rkt : rkd) + bc;
    float s = 0.f;
    const uint4* r4 = (const uint4*)row;
    #pragma unroll
    for (int it = 0; it < 2; ++it) {
        uint4 v = r4[tid * 2 + it];
        const u16* ph = (const u16*)&v;
        #pragma unroll
        for (int j = 0; j < 8; ++j) { float f = bf2f(ph[j]); s += f * f; }
    }
    #pragma unroll
    for (int off = 32; off > 0; off >>= 1) s += __shfl_down(s, off, 64);
    __shared__ float red[4];
    if ((tid & 63) == 0) red[tid >> 6] = s;
    __syncthreads();
    if (tid == 0) {
        float t = red[0] + red[1] + red[2] + red[3];
        out[0] = 1.0f / fmaxf(sqrtf(t), 1e-12f);
    }
}

// ---------------------------------------------------------------------------
// Scores partial (MFMA): Sp[which][bh][nc][c][d] = sum_{n in chunk} q[c][n]k[d][n]
// grid (8 nchunk, 64 bh, 2 which), block 256.
// ---------------------------------------------------------------------------
__global__ __launch_bounds__(256) void scores_mfma(
    const u16* __restrict__ q, const u16* __restrict__ Ktex, const u16* __restrict__ Kdep,
    float* __restrict__ Sp)
{
    int tid = threadIdx.x;
    int w = tid >> 6, lane = tid & 63;
    int lr = lane & 15, quad = lane >> 4;
    int nc = blockIdx.x, bh = blockIdx.y, which = blockIdx.z;
    int b = bh >> 2, h = bh & 3;
    const u16* Q = q + ((size_t)b * CCH + h * 64) * HWP;
    const u16* K = (which ? Kdep : Ktex) + ((size_t)b * CCH + h * 64) * HWP;

    f32x4 zz = {0.f, 0.f, 0.f, 0.f};
    f32x4 acc[4] = {zz, zz, zz, zz};
    const u16* Ab = Q + (size_t)(w * 16 + lr) * HWP + nc * 512 + quad * 8;
    const u16* Bb = K + (size_t)lr * HWP + nc * 512 + quad * 8;

    #pragma unroll 4
    for (int s = 0; s < 16; ++s) {
        int off = s * 32;
        bf16x8 a = *(const bf16x8*)(Ab + off);
        #pragma unroll
        for (int dj = 0; dj < 4; ++dj) {
            bf16x8 kb = *(const bf16x8*)(Bb + (size_t)dj * 16 * HWP + off);
            acc[dj] = __builtin_amdgcn_mfma_f32_16x16x32_bf16(a, kb, acc[dj], 0, 0, 0);
        }
    }
    float* out = Sp + (((size_t)(which * 64 + bh) * 8 + nc) * 4096);
    #pragma unroll
    for (int dj = 0; dj < 4; ++dj)
        #pragma unroll
        for (int r = 0; r < 4; ++r)
            out[(w * 16 + quad * 4 + r) * 64 + dj * 16 + lr] = acc[dj][r];
}

// ---------------------------------------------------------------------------
// Reduce partials + scale (rq*rk) + softmax + gate fold -> P bf16 [2][bh][c][d]
// grid (64 bh, 2 which), block 256.
// ---------------------------------------------------------------------------
__global__ __launch_bounds__(256) void softmax_kernel(
    const float* __restrict__ Sp, const float* __restrict__ rq,
    const float* __restrict__ rkt, const float* __restrict__ rkd,
    const float* __restrict__ ascale, u16* __restrict__ Pp)
{
    __shared__ float S[64][65];
    int tid = threadIdx.x;
    int bh = blockIdx.x, which = blockIdx.y;
    int b = bh >> 2, h = bh & 3;
    float g = 1.0f / (1.0f + expf(-ascale[h]));
    float gain = which ? (1.0f - g) : g;
    const float* base = Sp + ((size_t)(which * 64 + bh) * 8) * 4096;
    const float* rk  = (which ? rkd : rkt) + b * CCH + h * 64;
    const float* rqp = rq + b * CCH + h * 64;
    for (int i = tid; i < 4096; i += 256) {
        float s = 0.f;
        #pragma unroll
        for (int p = 0; p < 8; ++p) s += base[(size_t)p * 4096 + i];
        S[i >> 6][i & 63] = s * rqp[i >> 6] * rk[i & 63];
    }
    __syncthreads();
    if (tid < 64) {
        float mx = -1e30f;
        #pragma unroll 8
        for (int d = 0; d < 64; ++d) mx = fmaxf(mx, S[tid][d]);
        float sum = 0.f;
        #pragma unroll 8
        for (int d = 0; d < 64; ++d) { float e = expf(S[tid][d] - mx); S[tid][d] = e; sum += e; }
        float inv = gain / sum;
        u16* dst = Pp + ((size_t)(which * 64 + bh) * 64 + tid) * 64;
        #pragma unroll 8
        for (int d = 0; d < 64; ++d) dst[d] = f2bf_bits(S[tid][d] * inv);
    }
}

// ---------------------------------------------------------------------------
// PV (MFMA): qkvT[b][n][h*64+c] = sum_d P[c][d]*VT[n][d] over both sources.
// grid (16 nchunk, 64 bh), block 256.
// ---------------------------------------------------------------------------
__global__ __launch_bounds__(256) void pv_mfma(
    const u16* __restrict__ Pp, const u16* __restrict__ VtexT,
    const u16* __restrict__ VdepT, u16* __restrict__ qkvT)
{
    int tid = threadIdx.x;
    int w = tid >> 6, lane = tid & 63;
    int lr = lane & 15, quad = lane >> 4;
    int nc = blockIdx.x, bh = blockIdx.y;
    int b = bh >> 2, h = bh & 3;
    int n0 = nc * 256 + w * 64;

    f32x4 zz = {0.f, 0.f, 0.f, 0.f};
    f32x4 acc[4][4];
    #pragma unroll
    for (int i = 0; i < 4; ++i)
        #pragma unroll
        for (int j = 0; j < 4; ++j) acc[i][j] = zz;

    #pragma unroll
    for (int src = 0; src < 2; ++src) {
        const u16* P  = Pp + ((size_t)(src * 64 + bh) * 64) * 64;
        const u16* VT = (src ? VdepT : VtexT);
        const u16* Vb = VT + ((size_t)b * HWP + n0 + lr) * CCH + h * 64 + quad * 8;
        #pragma unroll
        for (int ks = 0; ks < 2; ++ks) {
            bf16x8 a[4], vv[4];
            #pragma unroll
            for (int ci = 0; ci < 4; ++ci)
                a[ci] = *(const bf16x8*)(P + (size_t)(ci * 16 + lr) * 64 + ks * 32 + quad * 8);
            #pragma unroll
            for (int nj = 0; nj < 4; ++nj)
                vv[nj] = *(const bf16x8*)(Vb + (size_t)nj * 16 * CCH + ks * 32);
            #pragma unroll
            for (int ci = 0; ci < 4; ++ci)
                #pragma unroll
                for (int nj = 0; nj < 4; ++nj)
                    acc[ci][nj] = __builtin_amdgcn_mfma_f32_16x16x32_bf16(a[ci], vv[nj], acc[ci][nj], 0, 0, 0);
        }
    }
    #pragma unroll
    for (int ci = 0; ci < 4; ++ci)
        #pragma unroll
        for (int nj = 0; nj < 4; ++nj) {
            int n = n0 + nj * 16 + lr;
            uint2 p;
            p.x = pack2(acc[ci][nj][0], acc[ci][nj][1]);
            p.y = pack2(acc[ci][nj][2], acc[ci][nj][3]);
            *(uint2*)(qkvT + ((size_t)b * HWP + n) * CCH + h * 64 + ci * 16 + quad * 4) = p;
        }
}

// ---------------------------------------------------------------------------
// Depthwise 3x3 + exact GELU, LDS-staged.
// Block = (8-ch group cg, half-plane nh, batch b). LDS: 8 planes of 34 rows
// (incl. zero-filled halo) x 64 cols, row stride 72 u16 (16B aligned).
// Each thread: 8 consecutive n x 8 ch; one ds_read_b128 per (ch,row);
// one 16B global store per n (8 channels packed).
// grid (32, 2, 16), block 256.
// ---------------------------------------------------------------------------
__global__ __launch_bounds__(256) void dwgelu_plane(
    const u16* __restrict__ y1, const float* __restrict__ dww, u16* __restrict__ y2T)
{
    __shared__ u16 plane[8 * 34 * 72];   // 39168 B
    __shared__ float sdw[72];
    int tid = threadIdx.x;
    int cg = blockIdx.x, nh = blockIdx.y, b = blockIdx.z;
    if (tid < 72) sdw[tid] = dww[cg * 72 + tid];

    // fill: 8 ch x 34 rows x 8 uint4-chunks = 2176 chunks
    for (int idx = tid; idx < 2176; idx += 256) {
        int cl  = idx / 272;
        int rem = idx - cl * 272;
        int r   = rem >> 3;
        int cc  = (rem & 7) << 3;
        int gr  = nh * 32 + r - 1;
        uint4 v = make_uint4(0u, 0u, 0u, 0u);
        if ((unsigned)gr < 64u)
            v = *(const uint4*)(y1 + ((size_t)b * CCH + cg * 8 + cl) * HWP + gr * 64 + cc);
        *(uint4*)&plane[cl * 2448 + r * 72 + cc] = v;
    }
    __syncthreads();

    int nb  = tid * 8;           // 0..2047 within half-plane
    int lrow = nb >> 6;          // 0..31
    int ww0  = nb & 63;          // multiple of 8
    float acc[8][8];
    #pragma unroll
    for (int i = 0; i < 8; ++i)
        #pragma unroll
        for (int c = 0; c < 8; ++c) acc[i][c] = 0.f;

    #pragma unroll
    for (int cl = 0; cl < 8; ++cl) {
        const u16* pl = &plane[cl * 2448];
        #pragma unroll
        for (int dy = 0; dy < 3; ++dy) {
            int pr = lrow + dy;              // plane row (halo handles borders)
            const u16* rowp = pl + pr * 72 + ww0;
            uint4 m = *(const uint4*)rowp;
            const u16* mh = (const u16*)&m;
            float s[10];
            #pragma unroll
            for (int j = 0; j < 8; ++j) s[j + 1] = bf2f(mh[j]);
            s[0] = (ww0 > 0)  ? bf2f(rowp[-1]) : 0.f;
            s[9] = (ww0 < 56) ? bf2f(rowp[8])  : 0.f;
            float w0 = sdw[cl * 9 + dy * 3 + 0];
            float w1 = sdw[cl * 9 + dy * 3 + 1];
            float w2 = sdw[cl * 9 + dy * 3 + 2];
            #pragma unroll
            for (int i = 0; i < 8; ++i)
                acc[i][cl] += s[i] * w0 + s[i + 1] * w1 + s[i + 2] * w2;
        }
    }

    size_t outbase = ((size_t)b * HWP + nh * 2048 + nb) * CCH + cg * 8;
    #pragma unroll
    for (int i = 0; i < 8; ++i) {
        u16 tmp[8];
        #pragma unroll
        for (int c = 0; c < 8; ++c) {
            float a = acc[i][c];
            tmp[c] = f2bf_bits(0.5f * a * (1.0f + erff(a * 0.70710678118654752f)));
        }
        *(uint4*)(y2T + outbase + (size_t)i * CCH) = *(uint4*)tmp;
    }
}

// ---------------------------------------------------------------------------
// Workspace (~210 MB): lnT 32 | q 32 | Ktex 32 | VtexT 32 | Kdep 32 | VdepT 32
//   | Sp 16 | Pp 1 | norms 48K | wbf 784K.  Aliases: qkvT=lnT; xT=qbuf;
//   y1=Ktex; y2T=VtexT.  x lives in d_out (fp32).
// ---------------------------------------------------------------------------
extern "C" void kernel_launch(void* const* d_in, const int* in_sizes, int n_in,
                              void* d_out, int out_size, void* d_ws, size_t ws_size,
                              hipStream_t stream)
{
    const float* img    = (const float*)d_in[0];
    const float* tex    = (const float*)d_in[1];
    const float* dep    = (const float*)d_in[2];
    const float* qnw    = (const float*)d_in[3];
    const float* qnb    = (const float*)d_in[4];
    const float* kvnw   = (const float*)d_in[5];
    const float* kvnb   = (const float*)d_in[6];
    const float* ascale = (const float*)d_in[7];
    const float* qpw    = (const float*)d_in[8];
    const float* kvpw   = (const float*)d_in[9];
    const float* opw    = (const float*)d_in[10];
    const float* opb    = (const float*)d_in[11];
    const float* fnw    = (const float*)d_in[12];
    const float* fnb    = (const float*)d_in[13];
    const float* fc1w   = (const float*)d_in[14];
    const float* dww    = (const float*)d_in[15];
    const float* fc2w   = (const float*)d_in[16];
    float* out = (float*)d_out;

    const size_t TEN = (size_t)BQ * CCH * HWP;   // 16,777,216
    char* p = (char*)d_ws;
    u16* lnT   = (u16*)p; p += TEN * 2;
    u16* qbuf  = (u16*)p; p += TEN * 2;
    u16* Ktex  = (u16*)p; p += TEN * 2;
    u16* VtexT = (u16*)p; p += TEN * 2;
    u16* Kdep  = (u16*)p; p += TEN * 2;
    u16* VdepT = (u16*)p; p += TEN * 2;
    float* Sp  = (float*)p; p += (size_t)8 * 2 * 64 * 4096 * 4;   // 16 MB
    u16* Pp    = (u16*)p;  p += (size_t)2 * 64 * 64 * 64 * 2;     // 1 MB
    float* rq  = (float*)p; p += (size_t)BQ * CCH * 4;
    float* rkt = (float*)p; p += (size_t)BQ * CCH * 4;
    float* rkd = (float*)p; p += (size_t)BQ * CCH * 4;
    u16* wq  = (u16*)p; p += 65536 * 2;
    u16* wkv = (u16*)p; p += 131072 * 2;
    u16* wo  = (u16*)p; p += 65536 * 2;
    u16* wf1 = (u16*)p; p += 65536 * 2;
    u16* wf2 = (u16*)p; p += 65536 * 2;
    u16* qkvT = lnT;     // alias
    u16* xT   = qbuf;    // alias
    u16* y1   = Ktex;    // alias
    u16* y2T  = VtexT;   // alias

    dim3 blk(256);
    // weight converts
    f2bf_kernel<<<64,  blk, 0, stream>>>(qpw,  wq,  16384);
    f2bf_kernel<<<128, blk, 0, stream>>>(kvpw, wkv, 32768);
    f2bf_kernel<<<64,  blk, 0, stream>>>(opw,  wo,  16384);
    f2bf_kernel<<<64,  blk, 0, stream>>>(fc1w, wf1, 16384);
    f2bf_kernel<<<64,  blk, 0, stream>>>(fc2w, wf2, 16384);
    // projections
    ln_t_f32<<<dim3(128, 16), blk, 0, stream>>>(img, qnw, qnb, lnT);
    gemmT<0><<<dim3(32, 2, 16), blk, 0, stream>>>(wq, lnT, qbuf, (u16*)0, (float*)0, (const float*)0, (const float*)0);
    ln_t_f32<<<dim3(128, 16), blk, 0, stream>>>(tex, kvnw, kvnb, lnT);
    gemmT<1><<<dim3(32, 4, 16), blk, 0, stream>>>(wkv, lnT, Ktex, VtexT, (float*)0, (const float*)0, (const float*)0);
    ln_t_f32<<<dim3(128, 16), blk, 0, stream>>>(dep, kvnw, kvnb, lnT);
    gemmT<1><<<dim3(32, 4, 16), blk, 0, stream>>>(wkv, lnT, Kdep, VdepT, (float*)0, (const float*)0, (const float*)0);
    // attention
    rownorm_kernel<<<3 * 4096, blk, 0, stream>>>(qbuf, Ktex, Kdep, rq, rkt, rkd);
    scores_mfma<<<dim3(8, 64, 2), blk, 0, stream>>>(qbuf, Ktex, Kdep, Sp);
    softmax_kernel<<<dim3(64, 2), blk, 0, stream>>>(Sp, rq, rkt, rkd, ascale, Pp);
    pv_mfma<<<dim3(16, 64), blk, 0, stream>>>(Pp, VtexT, VdepT, qkvT);
    // x = img + o_proj(qkv) + b  (fp32 in d_out, bf16 xT in ws)
    gemmT<2><<<dim3(32, 2, 16), blk, 0, stream>>>(wo, qkvT, (u16*)0, xT, out, opb, img);
    // FFN
    ln_t_bf16T<<<1024, blk, 0, stream>>>(xT, fnw, fnb, lnT);
    gemmT<0><<<dim3(32, 2, 16), blk, 0, stream>>>(wf1, lnT, y1, (u16*)0, (float*)0, (const float*)0, (const float*)0);
    dwgelu_plane<<<dim3(32, 2, 16), blk, 0, stream>>>(y1, dww, y2T);
    gemmT<3><<<dim3(32, 2, 16), blk, 0, stream>>>(wf2, y2T, (u16*)0, (u16*)0, out, (const float*)0, out);
}

// Round 2
// 632.636 us; speedup vs baseline: 1.6943x; 1.2642x over previous
//
#include <hip/hip_runtime.h>

// Problem constants
#define BQ   16
#define CCH  256
#define HWP  4096   // H*W

typedef unsigned short u16;
typedef unsigned int   u32;
typedef __attribute__((ext_vector_type(8))) short bf16x8;   // 8 bf16 (4 VGPRs)
typedef __attribute__((ext_vector_type(4))) float f32x4;    // MFMA C/D

__device__ __forceinline__ float bf2f(u16 h) {
    union { u32 u; float f; } v; v.u = (u32)h << 16; return v.f;
}
__device__ __forceinline__ u16 f2bf_bits(float f) {
    u32 u = __float_as_uint(f);
    u32 r = (u + 0x7fffu + ((u >> 16) & 1u)) >> 16;   // RNE
    return (u16)r;
}
__device__ __forceinline__ u32 pack2(float a, float b) {
    return (u32)f2bf_bits(a) | ((u32)f2bf_bits(b) << 16);
}
// async global->LDS, 16B per lane; lds dest = wave-uniform base + lane*16
__device__ __forceinline__ void gload16(const u16* g, u16* l) {
    __builtin_amdgcn_global_load_lds(
        (const __attribute__((address_space(1))) void*)g,
        (__attribute__((address_space(3))) void*)l, 16, 0, 0);
}

// ---------------------------------------------------------------------------
// fp32 -> bf16 weight convert. n4 = count/4.
// ---------------------------------------------------------------------------
__global__ __launch_bounds__(256) void f2bf_kernel(
    const float* __restrict__ src, u16* __restrict__ dst, int n4)
{
    int i = blockIdx.x * 256 + threadIdx.x;
    if (i < n4) {
        float4 v = ((const float4*)src)[i];
        uint2 p; p.x = pack2(v.x, v.y); p.y = pack2(v.z, v.w);
        ((uint2*)dst)[i] = p;
    }
}

// ---------------------------------------------------------------------------
// LayerNorm over C + transpose: x fp32 [b][c][n] -> outT bf16 [b][n][c].
// LDS-staged tile, 32 n x 256 c per block. grid (128, 16), block 256.
// ---------------------------------------------------------------------------
__global__ __launch_bounds__(256) void ln_t_f32(
    const float* __restrict__ x, const float* __restrict__ wgt,
    const float* __restrict__ bias, u16* __restrict__ outT)
{
    __shared__ float tile[32 * 257];   // [n][c], stride 257 floats
    __shared__ float ps[256], pss[256];
    __shared__ float smu[32], srs[32];
    __shared__ float sw[CCH], sb[CCH];
    int tid = threadIdx.x;
    sw[tid] = wgt[tid]; sb[tid] = bias[tid];

    int nl = tid & 31, cg = tid >> 5;        // n-lane, channel group
    int b  = blockIdx.y;
    int n0 = blockIdx.x * 32;
    const float* xp = x + (size_t)b * CCH * HWP + n0 + nl;

    float s = 0.f, ss = 0.f;
    #pragma unroll
    for (int j = 0; j < 32; ++j) {
        int c = cg * 32 + j;
        float v = xp[(size_t)c * HWP];
        tile[nl * 257 + c] = v;
        s += v; ss += v * v;
    }
    ps[tid] = s; pss[tid] = ss;
    __syncthreads();

    if (tid < 32) {
        float t = 0.f, tt = 0.f;
        #pragma unroll
        for (int g = 0; g < 8; ++g) { t += ps[g * 32 + tid]; tt += pss[g * 32 + tid]; }
        float u = t * (1.0f / CCH);
        smu[tid] = u;
        srs[tid] = rsqrtf(tt * (1.0f / CCH) - u * u + 1e-6f);
    }
    __syncthreads();

    int c0 = (tid & 31) * 8, nb = tid >> 5;  // lanes 0..31 -> consecutive c
    #pragma unroll
    for (int r = 0; r < 4; ++r) {
        int n = r * 8 + nb;
        float u = smu[n], rr = srs[n];
        u16 tmp[8];
        #pragma unroll
        for (int j = 0; j < 8; ++j) {
            float v = tile[n * 257 + c0 + j];
            tmp[j] = f2bf_bits(sw[c0 + j] * (v - u) * rr + sb[c0 + j]);
        }
        *(uint4*)(outT + ((size_t)b * HWP + n0 + n) * CCH + c0) = *(uint4*)tmp;
    }
}

// ---------------------------------------------------------------------------
// Same, but input already bf16 T-layout [b][n][c] (used for LN of x).
// 4 threads/row, quad shuffle-reduce. grid 1024, block 256.
// ---------------------------------------------------------------------------
__global__ __launch_bounds__(256) void ln_t_bf16T(
    const u16* __restrict__ xT, const float* __restrict__ wgt,
    const float* __restrict__ bias, u16* __restrict__ outT)
{
    __shared__ float sw[CCH], sb[CCH];
    int tid = threadIdx.x;
    sw[tid] = wgt[tid]; sb[tid] = bias[tid];
    __syncthreads();
    int gid = blockIdx.x * 256 + tid;
    int ng = gid >> 2, q = gid & 3;          // 4 threads per (b,n) row
    int b = ng >> 12, n = ng & 4095;
    const u16* xp = xT + ((size_t)b * HWP + n) * CCH + q * 64;
    uint4 w4[8];
    float s = 0.f, ss = 0.f;
    #pragma unroll
    for (int k = 0; k < 8; ++k) {
        w4[k] = *(const uint4*)(xp + k * 8);
        const u16* ph = (const u16*)&w4[k];
        #pragma unroll
        for (int j = 0; j < 8; ++j) { float v = bf2f(ph[j]); s += v; ss += v * v; }
    }
    s  += __shfl_xor(s, 1);  s  += __shfl_xor(s, 2);
    ss += __shfl_xor(ss, 1); ss += __shfl_xor(ss, 2);
    float u = s * (1.0f / CCH);
    float r = rsqrtf(ss * (1.0f / CCH) - u * u + 1e-6f);
    u16* op = outT + ((size_t)b * HWP + n) * CCH + q * 64;
    #pragma unroll
    for (int k = 0; k < 8; ++k) {
        const u16* ph = (const u16*)&w4[k];
        int cb = q * 64 + k * 8;
        u16 tmp[8];
        #pragma unroll
        for (int j = 0; j < 8; ++j)
            tmp[j] = f2bf_bits(sw[cb + j] * (bf2f(ph[j]) - u) * r + sb[cb + j]);
        *(uint4*)(op + k * 8) = *(uint4*)tmp;
    }
}

// ---------------------------------------------------------------------------
// MFMA GEMM: Out[b][m][n] = sum_k Wb[m][k] * XT[b][n][k]   (K=256)
// v2: m97 structure. 128x128 tile, BK=32, double-buffered LDS staged via
// global_load_lds width-16 (2 A + 2 B loads/thread/step), one barrier per
// K-step, ds_read_b128 fragments. 4 waves (2x2), 64x64 each.
// MODE 0: orig bf16 out                      (q, fc1)
// MODE 1: m<256 -> orig bf16 K; m>=256 -> T bf16 V        (kv)
// MODE 2: +bias +resF(img); fp32 orig outF (d_out) AND T bf16 outB (xT)
// MODE 3: +resF; fp32 orig outF (d_out)     (fc2)
// grid: (32, M/128, 16)
// ---------------------------------------------------------------------------
template<int MODE>
__global__ __launch_bounds__(256) void gemmT(
    const u16* __restrict__ Wb, const u16* __restrict__ XT,
    u16* __restrict__ outA, u16* __restrict__ outB,
    float* __restrict__ outF, const float* __restrict__ bias,
    const float* __restrict__ resF)
{
    // per buffer: A 128x32 (4096 u16) then B 128x32 (4096 u16) = 16 KB
    __shared__ __align__(16) u16 lds[2][8192];

    int tid = threadIdx.x;
    int w = tid >> 6, lane = tid & 63;
    int lr = lane & 15, quad = lane >> 4;
    int wm = w >> 1, wn = w & 1;
    int b   = blockIdx.z;
    int m0b = blockIdx.y * 128;
    int n0b = blockIdx.x * 128;
    int m0 = m0b + wm * 64;
    int n0 = n0b + wn * 64;

    // staging map: wave w, call c stages rows [w*32+c*16 + lane/4], col (lane&3)*8
    int srow = w * 32 + (lane >> 2);
    int scol = (lane & 3) * 8;
    const u16* gA = Wb + (size_t)(m0b + srow) * CCH + scol;
    const u16* gB = XT + ((size_t)b * HWP + n0b + srow) * CCH + scol;

    f32x4 zz = {0.f, 0.f, 0.f, 0.f};
    f32x4 acc[4][4];
    #pragma unroll
    for (int i = 0; i < 4; ++i)
        #pragma unroll
        for (int j = 0; j < 4; ++j) acc[i][j] = zz;

    const u16* Ard = &lds[0][0] + (size_t)(wm * 64 + lr) * 32 + quad * 8;
    const u16* Brd = &lds[0][4096] + (size_t)(wn * 64 + lr) * 32 + quad * 8;

    // prologue: stage k0=0 into buf 0
    #pragma unroll
    for (int c = 0; c < 2; ++c) {
        gload16(gA + (size_t)c * 16 * CCH, &lds[0][0]    + (w * 2 + c) * 512);
        gload16(gB + (size_t)c * 16 * CCH, &lds[0][4096] + (w * 2 + c) * 512);
    }
    __syncthreads();

    #pragma unroll
    for (int t = 0; t < 8; ++t) {
        int cur = t & 1;
        if (t < 7) {      // stage next K-chunk into the other buffer
            int kk = (t + 1) * 32;
            #pragma unroll
            for (int c = 0; c < 2; ++c) {
                gload16(gA + (size_t)c * 16 * CCH + kk, &lds[cur ^ 1][0]    + (w * 2 + c) * 512);
                gload16(gB + (size_t)c * 16 * CCH + kk, &lds[cur ^ 1][4096] + (w * 2 + c) * 512);
            }
        }
        bf16x8 a[4], bb[4];
        #pragma unroll
        for (int mi = 0; mi < 4; ++mi) a[mi]  = *(const bf16x8*)(Ard + cur * 8192 + mi * 16 * 32);
        #pragma unroll
        for (int nj = 0; nj < 4; ++nj) bb[nj] = *(const bf16x8*)(Brd + cur * 8192 + nj * 16 * 32);
        #pragma unroll
        for (int mi = 0; mi < 4; ++mi)
            #pragma unroll
            for (int nj = 0; nj < 4; ++nj)
                acc[mi][nj] = __builtin_amdgcn_mfma_f32_16x16x32_bf16(a[mi], bb[nj], acc[mi][nj], 0, 0, 0);
        __syncthreads();   // drains staged loads (vmcnt) + protects buffer reuse
    }

    #pragma unroll
    for (int mi = 0; mi < 4; ++mi) {
        int mbase = m0 + mi * 16 + quad * 4;   // 4 consecutive m via reg idx
        #pragma unroll
        for (int nj = 0; nj < 4; ++nj) {
            int n = n0 + nj * 16 + lr;
            if (MODE == 0 || (MODE == 1 && m0 < 256)) {
                size_t base = ((size_t)b * CCH + mbase) * HWP + n;
                #pragma unroll
                for (int r = 0; r < 4; ++r)
                    outA[base + (size_t)r * HWP] = f2bf_bits(acc[mi][nj][r]);
            } else if (MODE == 1) {            // V-half -> T layout
                uint2 p;
                p.x = pack2(acc[mi][nj][0], acc[mi][nj][1]);
                p.y = pack2(acc[mi][nj][2], acc[mi][nj][3]);
                *(uint2*)(outB + ((size_t)b * HWP + n) * CCH + (mbase - 256)) = p;
            } else if (MODE == 2) {
                float v[4];
                size_t rb = ((size_t)b * CCH + mbase) * HWP + n;
                #pragma unroll
                for (int r = 0; r < 4; ++r) {
                    v[r] = acc[mi][nj][r] + bias[mbase + r] + resF[rb + (size_t)r * HWP];
                    outF[rb + (size_t)r * HWP] = v[r];
                }
                uint2 p; p.x = pack2(v[0], v[1]); p.y = pack2(v[2], v[3]);
                *(uint2*)(outB + ((size_t)b * HWP + n) * CCH + mbase) = p;
            } else {                           // MODE 3
                size_t rb = ((size_t)b * CCH + mbase) * HWP + n;
                #pragma unroll
                for (int r = 0; r < 4; ++r)
                    outF[rb + (size_t)r * HWP] = acc[mi][nj][r] + resF[rb + (size_t)r * HWP];
            }
        }
    }
}

// ---------------------------------------------------------------------------
// Reciprocal L2 row norms over HW (vectorized uint4 loads).
// grid: 3*B*C blocks, block 256.
// ---------------------------------------------------------------------------
__global__ __launch_bounds__(256) void rownorm_kernel(
    const u16* __restrict__ q, const u16* __restrict__ Ktex, const u16* __restrict__ Kdep,
    float* __restrict__ rq, float* __restrict__ rkt, float* __restrict__ rkd)
{
    int tid = threadIdx.x;
    int idx = blockIdx.x;
    int which = idx >> 12;
    int bc = idx & 4095;
    const u16* row = (which == 0 ? q : which == 1 ? Ktex : Kdep) + (size_t)bc * HWP;
    float* out = (which == 0 ? rq : which == 1 ? rkt : rkd) + bc;
    float s = 0.f;
    const uint4* r4 = (const uint4*)row;
    #pragma unroll
    for (int it = 0; it < 2; ++it) {
        uint4 v = r4[tid * 2 + it];
        const u16* ph = (const u16*)&v;
        #pragma unroll
        for (int j = 0; j < 8; ++j) { float f = bf2f(ph[j]); s += f * f; }
    }
    #pragma unroll
    for (int off = 32; off > 0; off >>= 1) s += __shfl_down(s, off, 64);
    __shared__ float red[4];
    if ((tid & 63) == 0) red[tid >> 6] = s;
    __syncthreads();
    if (tid == 0) {
        float t = red[0] + red[1] + red[2] + red[3];
        out[0] = 1.0f / fmaxf(sqrtf(t), 1e-12f);
    }
}

// ---------------------------------------------------------------------------
// Scores partial (MFMA): Sp[which][bh][nc][c][d] = sum_{n in chunk} q[c][n]k[d][n]
// grid (8 nchunk, 64 bh, 2 which), block 256.
// ---------------------------------------------------------------------------
__global__ __launch_bounds__(256) void scores_mfma(
    const u16* __restrict__ q, const u16* __restrict__ Ktex, const u16* __restrict__ Kdep,
    float* __restrict__ Sp)
{
    int tid = threadIdx.x;
    int w = tid >> 6, lane = tid & 63;
    int lr = lane & 15, quad = lane >> 4;
    int nc = blockIdx.x, bh = blockIdx.y, which = blockIdx.z;
    int b = bh >> 2, h = bh & 3;
    const u16* Q = q + ((size_t)b * CCH + h * 64) * HWP;
    const u16* K = (which ? Kdep : Ktex) + ((size_t)b * CCH + h * 64) * HWP;

    f32x4 zz = {0.f, 0.f, 0.f, 0.f};
    f32x4 acc[4] = {zz, zz, zz, zz};
    const u16* Ab = Q + (size_t)(w * 16 + lr) * HWP + nc * 512 + quad * 8;
    const u16* Bb = K + (size_t)lr * HWP + nc * 512 + quad * 8;

    #pragma unroll 4
    for (int s = 0; s < 16; ++s) {
        int off = s * 32;
        bf16x8 a = *(const bf16x8*)(Ab + off);
        #pragma unroll
        for (int dj = 0; dj < 4; ++dj) {
            bf16x8 kb = *(const bf16x8*)(Bb + (size_t)dj * 16 * HWP + off);
            acc[dj] = __builtin_amdgcn_mfma_f32_16x16x32_bf16(a, kb, acc[dj], 0, 0, 0);
        }
    }
    float* out = Sp + (((size_t)(which * 64 + bh) * 8 + nc) * 4096);
    #pragma unroll
    for (int dj = 0; dj < 4; ++dj)
        #pragma unroll
        for (int r = 0; r < 4; ++r)
            out[(w * 16 + quad * 4 + r) * 64 + dj * 16 + lr] = acc[dj][r];
}

// ---------------------------------------------------------------------------
// Reduce partials + scale (rq*rk) + softmax + gate fold -> P bf16 [2][bh][c][d]
// grid (64 bh, 2 which), block 256.
// ---------------------------------------------------------------------------
__global__ __launch_bounds__(256) void softmax_kernel(
    const float* __restrict__ Sp, const float* __restrict__ rq,
    const float* __restrict__ rkt, const float* __restrict__ rkd,
    const float* __restrict__ ascale, u16* __restrict__ Pp)
{
    __shared__ float S[64][65];
    int tid = threadIdx.x;
    int bh = blockIdx.x, which = blockIdx.y;
    int b = bh >> 2, h = bh & 3;
    float g = 1.0f / (1.0f + expf(-ascale[h]));
    float gain = which ? (1.0f - g) : g;
    const float* base = Sp + ((size_t)(which * 64 + bh) * 8) * 4096;
    const float* rk  = (which ? rkd : rkt) + b * CCH + h * 64;
    const float* rqp = rq + b * CCH + h * 64;
    for (int i = tid; i < 4096; i += 256) {
        float s = 0.f;
        #pragma unroll
        for (int p = 0; p < 8; ++p) s += base[(size_t)p * 4096 + i];
        S[i >> 6][i & 63] = s * rqp[i >> 6] * rk[i & 63];
    }
    __syncthreads();
    if (tid < 64) {
        float mx = -1e30f;
        #pragma unroll 8
        for (int d = 0; d < 64; ++d) mx = fmaxf(mx, S[tid][d]);
        float sum = 0.f;
        #pragma unroll 8
        for (int d = 0; d < 64; ++d) { float e = expf(S[tid][d] - mx); S[tid][d] = e; sum += e; }
        float inv = gain / sum;
        u16* dst = Pp + ((size_t)(which * 64 + bh) * 64 + tid) * 64;
        #pragma unroll 8
        for (int d = 0; d < 64; ++d) dst[d] = f2bf_bits(S[tid][d] * inv);
    }
}

// ---------------------------------------------------------------------------
// PV (MFMA): qkvT[b][n][h*64+c] = sum_d P[c][d]*VT[n][d] over both sources.
// grid (16 nchunk, 64 bh), block 256.
// ---------------------------------------------------------------------------
__global__ __launch_bounds__(256) void pv_mfma(
    const u16* __restrict__ Pp, const u16* __restrict__ VtexT,
    const u16* __restrict__ VdepT, u16* __restrict__ qkvT)
{
    int tid = threadIdx.x;
    int w = tid >> 6, lane = tid & 63;
    int lr = lane & 15, quad = lane >> 4;
    int nc = blockIdx.x, bh = blockIdx.y;
    int b = bh >> 2, h = bh & 3;
    int n0 = nc * 256 + w * 64;

    f32x4 zz = {0.f, 0.f, 0.f, 0.f};
    f32x4 acc[4][4];
    #pragma unroll
    for (int i = 0; i < 4; ++i)
        #pragma unroll
        for (int j = 0; j < 4; ++j) acc[i][j] = zz;

    #pragma unroll
    for (int src = 0; src < 2; ++src) {
        const u16* P  = Pp + ((size_t)(src * 64 + bh) * 64) * 64;
        const u16* VT = (src ? VdepT : VtexT);
        const u16* Vb = VT + ((size_t)b * HWP + n0 + lr) * CCH + h * 64 + quad * 8;
        #pragma unroll
        for (int ks = 0; ks < 2; ++ks) {
            bf16x8 a[4], vv[4];
            #pragma unroll
            for (int ci = 0; ci < 4; ++ci)
                a[ci] = *(const bf16x8*)(P + (size_t)(ci * 16 + lr) * 64 + ks * 32 + quad * 8);
            #pragma unroll
            for (int nj = 0; nj < 4; ++nj)
                vv[nj] = *(const bf16x8*)(Vb + (size_t)nj * 16 * CCH + ks * 32);
            #pragma unroll
            for (int ci = 0; ci < 4; ++ci)
                #pragma unroll
                for (int nj = 0; nj < 4; ++nj)
                    acc[ci][nj] = __builtin_amdgcn_mfma_f32_16x16x32_bf16(a[ci], vv[nj], acc[ci][nj], 0, 0, 0);
        }
    }
    #pragma unroll
    for (int ci = 0; ci < 4; ++ci)
        #pragma unroll
        for (int nj = 0; nj < 4; ++nj) {
            int n = n0 + nj * 16 + lr;
            uint2 p;
            p.x = pack2(acc[ci][nj][0], acc[ci][nj][1]);
            p.y = pack2(acc[ci][nj][2], acc[ci][nj][3]);
            *(uint2*)(qkvT + ((size_t)b * HWP + n) * CCH + h * 64 + ci * 16 + quad * 4) = p;
        }
}

// ---------------------------------------------------------------------------
// Depthwise 3x3 + exact GELU, LDS-staged.
// grid (32, 2, 16), block 256.
// ---------------------------------------------------------------------------
__global__ __launch_bounds__(256) void dwgelu_plane(
    const u16* __restrict__ y1, const float* __restrict__ dww, u16* __restrict__ y2T)
{
    __shared__ u16 plane[8 * 34 * 72];   // 39168 B
    __shared__ float sdw[72];
    int tid = threadIdx.x;
    int cg = blockIdx.x, nh = blockIdx.y, b = blockIdx.z;
    if (tid < 72) sdw[tid] = dww[cg * 72 + tid];

    // fill: 8 ch x 34 rows x 8 uint4-chunks = 2176 chunks
    for (int idx = tid; idx < 2176; idx += 256) {
        int cl  = idx / 272;
        int rem = idx - cl * 272;
        int r   = rem >> 3;
        int cc  = (rem & 7) << 3;
        int gr  = nh * 32 + r - 1;
        uint4 v = make_uint4(0u, 0u, 0u, 0u);
        if ((unsigned)gr < 64u)
            v = *(const uint4*)(y1 + ((size_t)b * CCH + cg * 8 + cl) * HWP + gr * 64 + cc);
        *(uint4*)&plane[cl * 2448 + r * 72 + cc] = v;
    }
    __syncthreads();

    int nb  = tid * 8;           // 0..2047 within half-plane
    int lrow = nb >> 6;          // 0..31
    int ww0  = nb & 63;          // multiple of 8
    float acc[8][8];
    #pragma unroll
    for (int i = 0; i < 8; ++i)
        #pragma unroll
        for (int c = 0; c < 8; ++c) acc[i][c] = 0.f;

    #pragma unroll
    for (int cl = 0; cl < 8; ++cl) {
        const u16* pl = &plane[cl * 2448];
        #pragma unroll
        for (int dy = 0; dy < 3; ++dy) {
            int pr = lrow + dy;              // plane row (halo handles borders)
            const u16* rowp = pl + pr * 72 + ww0;
            uint4 m = *(const uint4*)rowp;
            const u16* mh = (const u16*)&m;
            float s[10];
            #pragma unroll
            for (int j = 0; j < 8; ++j) s[j + 1] = bf2f(mh[j]);
            s[0] = (ww0 > 0)  ? bf2f(rowp[-1]) : 0.f;
            s[9] = (ww0 < 56) ? bf2f(rowp[8])  : 0.f;
            float w0 = sdw[cl * 9 + dy * 3 + 0];
            float w1 = sdw[cl * 9 + dy * 3 + 1];
            float w2 = sdw[cl * 9 + dy * 3 + 2];
            #pragma unroll
            for (int i = 0; i < 8; ++i)
                acc[i][cl] += s[i] * w0 + s[i + 1] * w1 + s[i + 2] * w2;
        }
    }

    size_t outbase = ((size_t)b * HWP + nh * 2048 + nb) * CCH + cg * 8;
    #pragma unroll
    for (int i = 0; i < 8; ++i) {
        u16 tmp[8];
        #pragma unroll
        for (int c = 0; c < 8; ++c) {
            float a = acc[i][c];
            tmp[c] = f2bf_bits(0.5f * a * (1.0f + erff(a * 0.70710678118654752f)));
        }
        *(uint4*)(y2T + outbase + (size_t)i * CCH) = *(uint4*)tmp;
    }
}

// ---------------------------------------------------------------------------
// Workspace (~210 MB): lnT 32 | q 32 | Ktex 32 | VtexT 32 | Kdep 32 | VdepT 32
//   | Sp 16 | Pp 1 | norms 48K | wbf 784K.  Aliases: qkvT=lnT; xT=qbuf;
//   y1=Ktex; y2T=VtexT.  x lives in d_out (fp32).
// ---------------------------------------------------------------------------
extern "C" void kernel_launch(void* const* d_in, const int* in_sizes, int n_in,
                              void* d_out, int out_size, void* d_ws, size_t ws_size,
                              hipStream_t stream)
{
    const float* img    = (const float*)d_in[0];
    const float* tex    = (const float*)d_in[1];
    const float* dep    = (const float*)d_in[2];
    const float* qnw    = (const float*)d_in[3];
    const float* qnb    = (const float*)d_in[4];
    const float* kvnw   = (const float*)d_in[5];
    const float* kvnb   = (const float*)d_in[6];
    const float* ascale = (const float*)d_in[7];
    const float* qpw    = (const float*)d_in[8];
    const float* kvpw   = (const float*)d_in[9];
    const float* opw    = (const float*)d_in[10];
    const float* opb    = (const float*)d_in[11];
    const float* fnw    = (const float*)d_in[12];
    const float* fnb    = (const float*)d_in[13];
    const float* fc1w   = (const float*)d_in[14];
    const float* dww    = (const float*)d_in[15];
    const float* fc2w   = (const float*)d_in[16];
    float* out = (float*)d_out;

    const size_t TEN = (size_t)BQ * CCH * HWP;   // 16,777,216
    char* p = (char*)d_ws;
    u16* lnT   = (u16*)p; p += TEN * 2;
    u16* qbuf  = (u16*)p; p += TEN * 2;
    u16* Ktex  = (u16*)p; p += TEN * 2;
    u16* VtexT = (u16*)p; p += TEN * 2;
    u16* Kdep  = (u16*)p; p += TEN * 2;
    u16* VdepT = (u16*)p; p += TEN * 2;
    float* Sp  = (float*)p; p += (size_t)8 * 2 * 64 * 4096 * 4;   // 16 MB
    u16* Pp    = (u16*)p;  p += (size_t)2 * 64 * 64 * 64 * 2;     // 1 MB
    float* rq  = (float*)p; p += (size_t)BQ * CCH * 4;
    float* rkt = (float*)p; p += (size_t)BQ * CCH * 4;
    float* rkd = (float*)p; p += (size_t)BQ * CCH * 4;
    u16* wq  = (u16*)p; p += 65536 * 2;
    u16* wkv = (u16*)p; p += 131072 * 2;
    u16* wo  = (u16*)p; p += 65536 * 2;
    u16* wf1 = (u16*)p; p += 65536 * 2;
    u16* wf2 = (u16*)p; p += 65536 * 2;
    u16* qkvT = lnT;     // alias
    u16* xT   = qbuf;    // alias
    u16* y1   = Ktex;    // alias
    u16* y2T  = VtexT;   // alias

    dim3 blk(256);
    // weight converts
    f2bf_kernel<<<64,  blk, 0, stream>>>(qpw,  wq,  16384);
    f2bf_kernel<<<128, blk, 0, stream>>>(kvpw, wkv, 32768);
    f2bf_kernel<<<64,  blk, 0, stream>>>(opw,  wo,  16384);
    f2bf_kernel<<<64,  blk, 0, stream>>>(fc1w, wf1, 16384);
    f2bf_kernel<<<64,  blk, 0, stream>>>(fc2w, wf2, 16384);
    // projections
    ln_t_f32<<<dim3(128, 16), blk, 0, stream>>>(img, qnw, qnb, lnT);
    gemmT<0><<<dim3(32, 2, 16), blk, 0, stream>>>(wq, lnT, qbuf, (u16*)0, (float*)0, (const float*)0, (const float*)0);
    ln_t_f32<<<dim3(128, 16), blk, 0, stream>>>(tex, kvnw, kvnb, lnT);
    gemmT<1><<<dim3(32, 4, 16), blk, 0, stream>>>(wkv, lnT, Ktex, VtexT, (float*)0, (const float*)0, (const float*)0);
    ln_t_f32<<<dim3(128, 16), blk, 0, stream>>>(dep, kvnw, kvnb, lnT);
    gemmT<1><<<dim3(32, 4, 16), blk, 0, stream>>>(wkv, lnT, Kdep, VdepT, (float*)0, (const float*)0, (const float*)0);
    // attention
    rownorm_kernel<<<3 * 4096, blk, 0, stream>>>(qbuf, Ktex, Kdep, rq, rkt, rkd);
    scores_mfma<<<dim3(8, 64, 2), blk, 0, stream>>>(qbuf, Ktex, Kdep, Sp);
    softmax_kernel<<<dim3(64, 2), blk, 0, stream>>>(Sp, rq, rkt, rkd, ascale, Pp);
    pv_mfma<<<dim3(16, 64), blk, 0, stream>>>(Pp, VtexT, VdepT, qkvT);
    // x = img + o_proj(qkv) + b  (fp32 in d_out, bf16 xT in ws)
    gemmT<2><<<dim3(32, 2, 16), blk, 0, stream>>>(wo, qkvT, (u16*)0, xT, out, opb, img);
    // FFN
    ln_t_bf16T<<<1024, blk, 0, stream>>>(xT, fnw, fnb, lnT);
    gemmT<0><<<dim3(32, 2, 16), blk, 0, stream>>>(wf1, lnT, y1, (u16*)0, (float*)0, (const float*)0, (const float*)0);
    dwgelu_plane<<<dim3(32, 2, 16), blk, 0, stream>>>(y1, dww, y2T);
    gemmT<3><<<dim3(32, 2, 16), blk, 0, stream>>>(wf2, y2T, (u16*)0, (u16*)0, out, (const float*)0, out);
}

// Round 3
// 614.630 us; speedup vs baseline: 1.7439x; 1.0293x over previous
//
#include <hip/hip_runtime.h>

// Problem constants
#define BQ   16
#define CCH  256
#define HWP  4096   // H*W

typedef unsigned short u16;
typedef unsigned int   u32;
typedef __attribute__((ext_vector_type(8))) short bf16x8;   // 8 bf16 (4 VGPRs)
typedef __attribute__((ext_vector_type(4))) float f32x4;    // MFMA C/D

__device__ __forceinline__ float bf2f(u16 h) {
    union { u32 u; float f; } v; v.u = (u32)h << 16; return v.f;
}
__device__ __forceinline__ u16 f2bf_bits(float f) {
    u32 u = __float_as_uint(f);
    u32 r = (u + 0x7fffu + ((u >> 16) & 1u)) >> 16;   // RNE
    return (u16)r;
}
__device__ __forceinline__ u32 pack2(float a, float b) {
    return (u32)f2bf_bits(a) | ((u32)f2bf_bits(b) << 16);
}
// async global->LDS, 16B per lane; lds dest = wave-uniform base + lane*16
__device__ __forceinline__ void gload16(const u16* g, u16* l) {
    __builtin_amdgcn_global_load_lds(
        (const __attribute__((address_space(1))) void*)g,
        (__attribute__((address_space(3))) void*)l, 16, 0, 0);
}

// ---------------------------------------------------------------------------
// fp32 -> bf16 weight convert. n4 = count/4.
// ---------------------------------------------------------------------------
__global__ __launch_bounds__(256) void f2bf_kernel(
    const float* __restrict__ src, u16* __restrict__ dst, int n4)
{
    int i = blockIdx.x * 256 + threadIdx.x;
    if (i < n4) {
        float4 v = ((const float4*)src)[i];
        uint2 p; p.x = pack2(v.x, v.y); p.y = pack2(v.z, v.w);
        ((uint2*)dst)[i] = p;
    }
}

// ---------------------------------------------------------------------------
// LayerNorm over C + transpose: x fp32 [b][c][n] -> outT bf16 [b][n][c].
// LDS-staged tile, 32 n x 256 c per block. grid (128, 16), block 256.
// ---------------------------------------------------------------------------
__global__ __launch_bounds__(256) void ln_t_f32(
    const float* __restrict__ x, const float* __restrict__ wgt,
    const float* __restrict__ bias, u16* __restrict__ outT)
{
    __shared__ float tile[32 * 257];   // [n][c], stride 257 floats
    __shared__ float ps[256], pss[256];
    __shared__ float smu[32], srs[32];
    __shared__ float sw[CCH], sb[CCH];
    int tid = threadIdx.x;
    sw[tid] = wgt[tid]; sb[tid] = bias[tid];

    int nl = tid & 31, cg = tid >> 5;        // n-lane, channel group
    int b  = blockIdx.y;
    int n0 = blockIdx.x * 32;
    const float* xp = x + (size_t)b * CCH * HWP + n0 + nl;

    float s = 0.f, ss = 0.f;
    #pragma unroll
    for (int j = 0; j < 32; ++j) {
        int c = cg * 32 + j;
        float v = xp[(size_t)c * HWP];
        tile[nl * 257 + c] = v;
        s += v; ss += v * v;
    }
    ps[tid] = s; pss[tid] = ss;
    __syncthreads();

    if (tid < 32) {
        float t = 0.f, tt = 0.f;
        #pragma unroll
        for (int g = 0; g < 8; ++g) { t += ps[g * 32 + tid]; tt += pss[g * 32 + tid]; }
        float u = t * (1.0f / CCH);
        smu[tid] = u;
        srs[tid] = rsqrtf(tt * (1.0f / CCH) - u * u + 1e-6f);
    }
    __syncthreads();

    int c0 = (tid & 31) * 8, nb = tid >> 5;  // lanes 0..31 -> consecutive c
    #pragma unroll
    for (int r = 0; r < 4; ++r) {
        int n = r * 8 + nb;
        float u = smu[n], rr = srs[n];
        u16 tmp[8];
        #pragma unroll
        for (int j = 0; j < 8; ++j) {
            float v = tile[n * 257 + c0 + j];
            tmp[j] = f2bf_bits(sw[c0 + j] * (v - u) * rr + sb[c0 + j]);
        }
        *(uint4*)(outT + ((size_t)b * HWP + n0 + n) * CCH + c0) = *(uint4*)tmp;
    }
}

// ---------------------------------------------------------------------------
// Same, but input already bf16 T-layout [b][n][c] (used for LN of x).
// 4 threads/row, quad shuffle-reduce. grid 1024, block 256.
// ---------------------------------------------------------------------------
__global__ __launch_bounds__(256) void ln_t_bf16T(
    const u16* __restrict__ xT, const float* __restrict__ wgt,
    const float* __restrict__ bias, u16* __restrict__ outT)
{
    __shared__ float sw[CCH], sb[CCH];
    int tid = threadIdx.x;
    sw[tid] = wgt[tid]; sb[tid] = bias[tid];
    __syncthreads();
    int gid = blockIdx.x * 256 + tid;
    int ng = gid >> 2, q = gid & 3;          // 4 threads per (b,n) row
    int b = ng >> 12, n = ng & 4095;
    const u16* xp = xT + ((size_t)b * HWP + n) * CCH + q * 64;
    uint4 w4[8];
    float s = 0.f, ss = 0.f;
    #pragma unroll
    for (int k = 0; k < 8; ++k) {
        w4[k] = *(const uint4*)(xp + k * 8);
        const u16* ph = (const u16*)&w4[k];
        #pragma unroll
        for (int j = 0; j < 8; ++j) { float v = bf2f(ph[j]); s += v; ss += v * v; }
    }
    s  += __shfl_xor(s, 1);  s  += __shfl_xor(s, 2);
    ss += __shfl_xor(ss, 1); ss += __shfl_xor(ss, 2);
    float u = s * (1.0f / CCH);
    float r = rsqrtf(ss * (1.0f / CCH) - u * u + 1e-6f);
    u16* op = outT + ((size_t)b * HWP + n) * CCH + q * 64;
    #pragma unroll
    for (int k = 0; k < 8; ++k) {
        const u16* ph = (const u16*)&w4[k];
        int cb = q * 64 + k * 8;
        u16 tmp[8];
        #pragma unroll
        for (int j = 0; j < 8; ++j)
            tmp[j] = f2bf_bits(sw[cb + j] * (bf2f(ph[j]) - u) * r + sb[cb + j]);
        *(uint4*)(op + k * 8) = *(uint4*)tmp;
    }
}

// ---------------------------------------------------------------------------
// MFMA GEMM: Out[b][m][n] = sum_k Wb[m][k] * XT[b][n][k]   (K=256)
// m97 structure + LDS-transposed epilogues (v3):
//   all outputs staged through the (freed) 32KB staging LDS with XOR-swizzled
//   16B chunks, then stored as full 128/256B contiguous runs.
// MODE 0: orig bf16 out                      (q, fc1)
// MODE 1: m<256 -> orig bf16 K; m>=256 -> T bf16 V        (kv)
// MODE 2: +bias +resF(img); fp32 orig outF (d_out, scalar) AND T bf16 outB (xT)
// MODE 3: +resF; fp32 orig outF via 2-pass f32 tile (float4 ld/st)
// grid: (32, M/128, 16)
// ---------------------------------------------------------------------------
template<int MODE>
__global__ __launch_bounds__(256) void gemmT(
    const u16* __restrict__ Wb, const u16* __restrict__ XT,
    u16* __restrict__ outA, u16* __restrict__ outB,
    float* __restrict__ outF, const float* __restrict__ bias,
    const float* __restrict__ resF)
{
    // per buffer: A 128x32 (4096 u16) then B 128x32 (4096 u16) = 16 KB
    __shared__ __align__(16) u16 lds[2][8192];

    int tid = threadIdx.x;
    int w = tid >> 6, lane = tid & 63;
    int lr = lane & 15, quad = lane >> 4;
    int wm = w >> 1, wn = w & 1;
    int b   = blockIdx.z;
    int m0b = blockIdx.y * 128;
    int n0b = blockIdx.x * 128;
    int m0 = m0b + wm * 64;
    int n0 = n0b + wn * 64;

    // staging map: wave w, call c stages rows [w*32+c*16 + lane/4], col (lane&3)*8
    int srow = w * 32 + (lane >> 2);
    int scol = (lane & 3) * 8;
    const u16* gA = Wb + (size_t)(m0b + srow) * CCH + scol;
    const u16* gB = XT + ((size_t)b * HWP + n0b + srow) * CCH + scol;

    f32x4 zz = {0.f, 0.f, 0.f, 0.f};
    f32x4 acc[4][4];
    #pragma unroll
    for (int i = 0; i < 4; ++i)
        #pragma unroll
        for (int j = 0; j < 4; ++j) acc[i][j] = zz;

    const u16* Ard = &lds[0][0] + (size_t)(wm * 64 + lr) * 32 + quad * 8;
    const u16* Brd = &lds[0][4096] + (size_t)(wn * 64 + lr) * 32 + quad * 8;

    // prologue: stage k0=0 into buf 0
    #pragma unroll
    for (int c = 0; c < 2; ++c) {
        gload16(gA + (size_t)c * 16 * CCH, &lds[0][0]    + (w * 2 + c) * 512);
        gload16(gB + (size_t)c * 16 * CCH, &lds[0][4096] + (w * 2 + c) * 512);
    }
    __syncthreads();

    #pragma unroll
    for (int t = 0; t < 8; ++t) {
        int cur = t & 1;
        if (t < 7) {      // stage next K-chunk into the other buffer
            int kk = (t + 1) * 32;
            #pragma unroll
            for (int c = 0; c < 2; ++c) {
                gload16(gA + (size_t)c * 16 * CCH + kk, &lds[cur ^ 1][0]    + (w * 2 + c) * 512);
                gload16(gB + (size_t)c * 16 * CCH + kk, &lds[cur ^ 1][4096] + (w * 2 + c) * 512);
            }
        }
        bf16x8 a[4], bb[4];
        #pragma unroll
        for (int mi = 0; mi < 4; ++mi) a[mi]  = *(const bf16x8*)(Ard + cur * 8192 + mi * 16 * 32);
        #pragma unroll
        for (int nj = 0; nj < 4; ++nj) bb[nj] = *(const bf16x8*)(Brd + cur * 8192 + nj * 16 * 32);
        #pragma unroll
        for (int mi = 0; mi < 4; ++mi)
            #pragma unroll
            for (int nj = 0; nj < 4; ++nj)
                acc[mi][nj] = __builtin_amdgcn_mfma_f32_16x16x32_bf16(a[mi], bb[nj], acc[mi][nj], 0, 0, 0);
        __syncthreads();   // drains staged loads (vmcnt) + protects buffer reuse
    }

    // ---- epilogues: LDS (now free) used as a transpose stage -------------
    char* tile = (char*)&lds[0][0];    // 32 KB

    if (MODE == 0 || (MODE == 1 && m0b < 256)) {
        // orig bf16 [b][m][n]: tile [128m][128n] u16, XOR-swizzled 16B chunks
        #pragma unroll
        for (int mi = 0; mi < 4; ++mi) {
            int mloc = wm * 64 + mi * 16 + quad * 4;
            #pragma unroll
            for (int nj = 0; nj < 4; ++nj) {
                int nl = wn * 64 + nj * 16 + lr;
                #pragma unroll
                for (int r = 0; r < 4; ++r) {
                    int m = mloc + r;
                    *(u16*)(tile + m * 256 + ((nl * 2) ^ ((m & 7) << 4))) =
                        f2bf_bits(acc[mi][nj][r]);
                }
            }
        }
        __syncthreads();
        #pragma unroll
        for (int p = 0; p < 8; ++p) {
            int cid = p * 256 + tid;
            int row = cid >> 4, ch = cid & 15;
            uint4 v = *(const uint4*)(tile + row * 256 + ((ch * 16) ^ ((row & 7) << 4)));
            *(uint4*)(outA + ((size_t)b * CCH + m0b + row) * HWP + n0b + ch * 8) = v;
        }
    } else if (MODE == 1) {
        // V-half -> T [b][n][c]: tile [128n][128m] u16, uint2 writes
        #pragma unroll
        for (int mi = 0; mi < 4; ++mi) {
            int mloc = wm * 64 + mi * 16 + quad * 4;
            #pragma unroll
            for (int nj = 0; nj < 4; ++nj) {
                int nl = wn * 64 + nj * 16 + lr;
                uint2 pp;
                pp.x = pack2(acc[mi][nj][0], acc[mi][nj][1]);
                pp.y = pack2(acc[mi][nj][2], acc[mi][nj][3]);
                *(uint2*)(tile + nl * 256 + ((mloc * 2) ^ ((nl & 7) << 4))) = pp;
            }
        }
        __syncthreads();
        int cbase = m0b - 256;
        #pragma unroll
        for (int p = 0; p < 8; ++p) {
            int cid = p * 256 + tid;
            int row = cid >> 4, ch = cid & 15;
            uint4 v = *(const uint4*)(tile + row * 256 + ((ch * 16) ^ ((row & 7) << 4)));
            *(uint4*)(outB + ((size_t)b * HWP + n0b + row) * CCH + cbase + ch * 8) = v;
        }
    } else if (MODE == 2) {
        // fp32 out scalar (needs bias+res anyway) + vectorized T bf16 (xT)
        #pragma unroll
        for (int mi = 0; mi < 4; ++mi) {
            int mbase = m0 + mi * 16 + quad * 4;
            int mloc  = wm * 64 + mi * 16 + quad * 4;
            #pragma unroll
            for (int nj = 0; nj < 4; ++nj) {
                int n  = n0 + nj * 16 + lr;
                int nl = wn * 64 + nj * 16 + lr;
                float v[4];
                size_t rb = ((size_t)b * CCH + mbase) * HWP + n;
                #pragma unroll
                for (int r = 0; r < 4; ++r) {
                    v[r] = acc[mi][nj][r] + bias[mbase + r] + resF[rb + (size_t)r * HWP];
                    outF[rb + (size_t)r * HWP] = v[r];
                }
                uint2 pp; pp.x = pack2(v[0], v[1]); pp.y = pack2(v[2], v[3]);
                *(uint2*)(tile + nl * 256 + ((mloc * 2) ^ ((nl & 7) << 4))) = pp;
            }
        }
        __syncthreads();
        #pragma unroll
        for (int p = 0; p < 8; ++p) {
            int cid = p * 256 + tid;
            int row = cid >> 4, ch = cid & 15;
            uint4 v = *(const uint4*)(tile + row * 256 + ((ch * 16) ^ ((row & 7) << 4)));
            *(uint4*)(outB + ((size_t)b * HWP + n0b + row) * CCH + m0b + ch * 8) = v;
        }
    } else {
        // MODE 3: fp32 out += resF, two n-half passes via [128m][64n] f32 tile
        #pragma unroll
        for (int pass = 0; pass < 2; ++pass) {
            if (wn == pass) {
                #pragma unroll
                for (int mi = 0; mi < 4; ++mi) {
                    #pragma unroll
                    for (int nj = 0; nj < 4; ++nj) {
                        int nin = nj * 16 + lr;
                        #pragma unroll
                        for (int r = 0; r < 4; ++r) {
                            int m = wm * 64 + mi * 16 + quad * 4 + r;
                            *(u32*)(tile + m * 256 + ((nin * 4) ^ ((m & 7) << 4))) =
                                __float_as_uint(acc[mi][nj][r]);
                        }
                    }
                }
            }
            __syncthreads();
            #pragma unroll
            for (int p = 0; p < 8; ++p) {
                int cid = p * 256 + tid;
                int row = cid >> 4, ch = cid & 15;
                float4 v = *(const float4*)(tile + row * 256 + ((ch * 16) ^ ((row & 7) << 4)));
                size_t g = ((size_t)b * CCH + m0b + row) * HWP + n0b + pass * 64 + ch * 4;
                float4 rr = *(const float4*)(resF + g);
                v.x += rr.x; v.y += rr.y; v.z += rr.z; v.w += rr.w;
                *(float4*)(outF + g) = v;
            }
            if (pass == 0) __syncthreads();
        }
    }
}

// ---------------------------------------------------------------------------
// Reciprocal L2 row norms over HW (vectorized uint4 loads).
// grid: 3*B*C blocks, block 256.
// ---------------------------------------------------------------------------
__global__ __launch_bounds__(256) void rownorm_kernel(
    const u16* __restrict__ q, const u16* __restrict__ Ktex, const u16* __restrict__ Kdep,
    float* __restrict__ rq, float* __restrict__ rkt, float* __restrict__ rkd)
{
    int tid = threadIdx.x;
    int idx = blockIdx.x;
    int which = idx >> 12;
    int bc = idx & 4095;
    const u16* row = (which == 0 ? q : which == 1 ? Ktex : Kdep) + (size_t)bc * HWP;
    float* out = (which == 0 ? rq : which == 1 ? rkt : rkd) + bc;
    float s = 0.f;
    const uint4* r4 = (const uint4*)row;
    #pragma unroll
    for (int it = 0; it < 2; ++it) {
        uint4 v = r4[tid * 2 + it];
        const u16* ph = (const u16*)&v;
        #pragma unroll
        for (int j = 0; j < 8; ++j) { float f = bf2f(ph[j]); s += f * f; }
    }
    #pragma unroll
    for (int off = 32; off > 0; off >>= 1) s += __shfl_down(s, off, 64);
    __shared__ float red[4];
    if ((tid & 63) == 0) red[tid >> 6] = s;
    __syncthreads();
    if (tid == 0) {
        float t = red[0] + red[1] + red[2] + red[3];
        out[0] = 1.0f / fmaxf(sqrtf(t), 1e-12f);
    }
}

// ---------------------------------------------------------------------------
// Scores partial (MFMA): Sp[which][bh][nc][c][d] = sum_{n in chunk} q[c][n]k[d][n]
// grid (8 nchunk, 64 bh, 2 which), block 256.
// ---------------------------------------------------------------------------
__global__ __launch_bounds__(256) void scores_mfma(
    const u16* __restrict__ q, const u16* __restrict__ Ktex, const u16* __restrict__ Kdep,
    float* __restrict__ Sp)
{
    int tid = threadIdx.x;
    int w = tid >> 6, lane = tid & 63;
    int lr = lane & 15, quad = lane >> 4;
    int nc = blockIdx.x, bh = blockIdx.y, which = blockIdx.z;
    int b = bh >> 2, h = bh & 3;
    const u16* Q = q + ((size_t)b * CCH + h * 64) * HWP;
    const u16* K = (which ? Kdep : Ktex) + ((size_t)b * CCH + h * 64) * HWP;

    f32x4 zz = {0.f, 0.f, 0.f, 0.f};
    f32x4 acc[4] = {zz, zz, zz, zz};
    const u16* Ab = Q + (size_t)(w * 16 + lr) * HWP + nc * 512 + quad * 8;
    const u16* Bb = K + (size_t)lr * HWP + nc * 512 + quad * 8;

    #pragma unroll 4
    for (int s = 0; s < 16; ++s) {
        int off = s * 32;
        bf16x8 a = *(const bf16x8*)(Ab + off);
        #pragma unroll
        for (int dj = 0; dj < 4; ++dj) {
            bf16x8 kb = *(const bf16x8*)(Bb + (size_t)dj * 16 * HWP + off);
            acc[dj] = __builtin_amdgcn_mfma_f32_16x16x32_bf16(a, kb, acc[dj], 0, 0, 0);
        }
    }
    float* out = Sp + (((size_t)(which * 64 + bh) * 8 + nc) * 4096);
    #pragma unroll
    for (int dj = 0; dj < 4; ++dj)
        #pragma unroll
        for (int r = 0; r < 4; ++r)
            out[(w * 16 + quad * 4 + r) * 64 + dj * 16 + lr] = acc[dj][r];
}

// ---------------------------------------------------------------------------
// Reduce partials + scale (rq*rk) + softmax + gate fold -> P bf16 [2][bh][c][d]
// grid (64 bh, 2 which), block 256.
// ---------------------------------------------------------------------------
__global__ __launch_bounds__(256) void softmax_kernel(
    const float* __restrict__ Sp, const float* __restrict__ rq,
    const float* __restrict__ rkt, const float* __restrict__ rkd,
    const float* __restrict__ ascale, u16* __restrict__ Pp)
{
    __shared__ float S[64][65];
    int tid = threadIdx.x;
    int bh = blockIdx.x, which = blockIdx.y;
    int b = bh >> 2, h = bh & 3;
    float g = 1.0f / (1.0f + expf(-ascale[h]));
    float gain = which ? (1.0f - g) : g;
    const float* base = Sp + ((size_t)(which * 64 + bh) * 8) * 4096;
    const float* rk  = (which ? rkd : rkt) + b * CCH + h * 64;
    const float* rqp = rq + b * CCH + h * 64;
    for (int i = tid; i < 4096; i += 256) {
        float s = 0.f;
        #pragma unroll
        for (int p = 0; p < 8; ++p) s += base[(size_t)p * 4096 + i];
        S[i >> 6][i & 63] = s * rqp[i >> 6] * rk[i & 63];
    }
    __syncthreads();
    if (tid < 64) {
        float mx = -1e30f;
        #pragma unroll 8
        for (int d = 0; d < 64; ++d) mx = fmaxf(mx, S[tid][d]);
        float sum = 0.f;
        #pragma unroll 8
        for (int d = 0; d < 64; ++d) { float e = expf(S[tid][d] - mx); S[tid][d] = e; sum += e; }
        float inv = gain / sum;
        u16* dst = Pp + ((size_t)(which * 64 + bh) * 64 + tid) * 64;
        #pragma unroll 8
        for (int d = 0; d < 64; ++d) dst[d] = f2bf_bits(S[tid][d] * inv);
    }
}

// ---------------------------------------------------------------------------
// PV (MFMA): qkvT[b][n][h*64+c] = sum_d P[c][d]*VT[n][d] over both sources.
// grid (16 nchunk, 64 bh), block 256.
// ---------------------------------------------------------------------------
__global__ __launch_bounds__(256) void pv_mfma(
    const u16* __restrict__ Pp, const u16* __restrict__ VtexT,
    const u16* __restrict__ VdepT, u16* __restrict__ qkvT)
{
    int tid = threadIdx.x;
    int w = tid >> 6, lane = tid & 63;
    int lr = lane & 15, quad = lane >> 4;
    int nc = blockIdx.x, bh = blockIdx.y;
    int b = bh >> 2, h = bh & 3;
    int n0 = nc * 256 + w * 64;

    f32x4 zz = {0.f, 0.f, 0.f, 0.f};
    f32x4 acc[4][4];
    #pragma unroll
    for (int i = 0; i < 4; ++i)
        #pragma unroll
        for (int j = 0; j < 4; ++j) acc[i][j] = zz;

    #pragma unroll
    for (int src = 0; src < 2; ++src) {
        const u16* P  = Pp + ((size_t)(src * 64 + bh) * 64) * 64;
        const u16* VT = (src ? VdepT : VtexT);
        const u16* Vb = VT + ((size_t)b * HWP + n0 + lr) * CCH + h * 64 + quad * 8;
        #pragma unroll
        for (int ks = 0; ks < 2; ++ks) {
            bf16x8 a[4], vv[4];
            #pragma unroll
            for (int ci = 0; ci < 4; ++ci)
                a[ci] = *(const bf16x8*)(P + (size_t)(ci * 16 + lr) * 64 + ks * 32 + quad * 8);
            #pragma unroll
            for (int nj = 0; nj < 4; ++nj)
                vv[nj] = *(const bf16x8*)(Vb + (size_t)nj * 16 * CCH + ks * 32);
            #pragma unroll
            for (int ci = 0; ci < 4; ++ci)
                #pragma unroll
                for (int nj = 0; nj < 4; ++nj)
                    acc[ci][nj] = __builtin_amdgcn_mfma_f32_16x16x32_bf16(a[ci], vv[nj], acc[ci][nj], 0, 0, 0);
        }
    }
    #pragma unroll
    for (int ci = 0; ci < 4; ++ci)
        #pragma unroll
        for (int nj = 0; nj < 4; ++nj) {
            int n = n0 + nj * 16 + lr;
            uint2 p;
            p.x = pack2(acc[ci][nj][0], acc[ci][nj][1]);
            p.y = pack2(acc[ci][nj][2], acc[ci][nj][3]);
            *(uint2*)(qkvT + ((size_t)b * HWP + n) * CCH + h * 64 + ci * 16 + quad * 4) = p;
        }
}

// ---------------------------------------------------------------------------
// Depthwise 3x3 + exact GELU, LDS-staged.
// grid (32, 2, 16), block 256.
// ---------------------------------------------------------------------------
__global__ __launch_bounds__(256) void dwgelu_plane(
    const u16* __restrict__ y1, const float* __restrict__ dww, u16* __restrict__ y2T)
{
    __shared__ u16 plane[8 * 34 * 72];   // 39168 B
    __shared__ float sdw[72];
    int tid = threadIdx.x;
    int cg = blockIdx.x, nh = blockIdx.y, b = blockIdx.z;
    if (tid < 72) sdw[tid] = dww[cg * 72 + tid];

    // fill: 8 ch x 34 rows x 8 uint4-chunks = 2176 chunks
    for (int idx = tid; idx < 2176; idx += 256) {
        int cl  = idx / 272;
        int rem = idx - cl * 272;
        int r   = rem >> 3;
        int cc  = (rem & 7) << 3;
        int gr  = nh * 32 + r - 1;
        uint4 v = make_uint4(0u, 0u, 0u, 0u);
        if ((unsigned)gr < 64u)
            v = *(const uint4*)(y1 + ((size_t)b * CCH + cg * 8 + cl) * HWP + gr * 64 + cc);
        *(uint4*)&plane[cl * 2448 + r * 72 + cc] = v;
    }
    __syncthreads();

    int nb  = tid * 8;           // 0..2047 within half-plane
    int lrow = nb >> 6;          // 0..31
    int ww0  = nb & 63;          // multiple of 8
    float acc[8][8];
    #pragma unroll
    for (int i = 0; i < 8; ++i)
        #pragma unroll
        for (int c = 0; c < 8; ++c) acc[i][c] = 0.f;

    #pragma unroll
    for (int cl = 0; cl < 8; ++cl) {
        const u16* pl = &plane[cl * 2448];
        #pragma unroll
        for (int dy = 0; dy < 3; ++dy) {
            int pr = lrow + dy;              // plane row (halo handles borders)
            const u16* rowp = pl + pr * 72 + ww0;
            uint4 m = *(const uint4*)rowp;
            const u16* mh = (const u16*)&m;
            float s[10];
            #pragma unroll
            for (int j = 0; j < 8; ++j) s[j + 1] = bf2f(mh[j]);
            s[0] = (ww0 > 0)  ? bf2f(rowp[-1]) : 0.f;
            s[9] = (ww0 < 56) ? bf2f(rowp[8])  : 0.f;
            float w0 = sdw[cl * 9 + dy * 3 + 0];
            float w1 = sdw[cl * 9 + dy * 3 + 1];
            float w2 = sdw[cl * 9 + dy * 3 + 2];
            #pragma unroll
            for (int i = 0; i < 8; ++i)
                acc[i][cl] += s[i] * w0 + s[i + 1] * w1 + s[i + 2] * w2;
        }
    }

    size_t outbase = ((size_t)b * HWP + nh * 2048 + nb) * CCH + cg * 8;
    #pragma unroll
    for (int i = 0; i < 8; ++i) {
        u16 tmp[8];
        #pragma unroll
        for (int c = 0; c < 8; ++c) {
            float a = acc[i][c];
            tmp[c] = f2bf_bits(0.5f * a * (1.0f + erff(a * 0.70710678118654752f)));
        }
        *(uint4*)(y2T + outbase + (size_t)i * CCH) = *(uint4*)tmp;
    }
}

// ---------------------------------------------------------------------------
// Workspace (~210 MB): lnT 32 | q 32 | Ktex 32 | VtexT 32 | Kdep 32 | VdepT 32
//   | Sp 16 | Pp 1 | norms 48K | wbf 784K.  Aliases: qkvT=lnT; xT=qbuf;
//   y1=Ktex; y2T=VtexT.  x lives in d_out (fp32).
// ---------------------------------------------------------------------------
extern "C" void kernel_launch(void* const* d_in, const int* in_sizes, int n_in,
                              void* d_out, int out_size, void* d_ws, size_t ws_size,
                              hipStream_t stream)
{
    const float* img    = (const float*)d_in[0];
    const float* tex    = (const float*)d_in[1];
    const float* dep    = (const float*)d_in[2];
    const float* qnw    = (const float*)d_in[3];
    const float* qnb    = (const float*)d_in[4];
    const float* kvnw   = (const float*)d_in[5];
    const float* kvnb   = (const float*)d_in[6];
    const float* ascale = (const float*)d_in[7];
    const float* qpw    = (const float*)d_in[8];
    const float* kvpw   = (const float*)d_in[9];
    const float* opw    = (const float*)d_in[10];
    const float* opb    = (const float*)d_in[11];
    const float* fnw    = (const float*)d_in[12];
    const float* fnb    = (const float*)d_in[13];
    const float* fc1w   = (const float*)d_in[14];
    const float* dww    = (const float*)d_in[15];
    const float* fc2w   = (const float*)d_in[16];
    float* out = (float*)d_out;

    const size_t TEN = (size_t)BQ * CCH * HWP;   // 16,777,216
    char* p = (char*)d_ws;
    u16* lnT   = (u16*)p; p += TEN * 2;
    u16* qbuf  = (u16*)p; p += TEN * 2;
    u16* Ktex  = (u16*)p; p += TEN * 2;
    u16* VtexT = (u16*)p; p += TEN * 2;
    u16* Kdep  = (u16*)p; p += TEN * 2;
    u16* VdepT = (u16*)p; p += TEN * 2;
    float* Sp  = (float*)p; p += (size_t)8 * 2 * 64 * 4096 * 4;   // 16 MB
    u16* Pp    = (u16*)p;  p += (size_t)2 * 64 * 64 * 64 * 2;     // 1 MB
    float* rq  = (float*)p; p += (size_t)BQ * CCH * 4;
    float* rkt = (float*)p; p += (size_t)BQ * CCH * 4;
    float* rkd = (float*)p; p += (size_t)BQ * CCH * 4;
    u16* wq  = (u16*)p; p += 65536 * 2;
    u16* wkv = (u16*)p; p += 131072 * 2;
    u16* wo  = (u16*)p; p += 65536 * 2;
    u16* wf1 = (u16*)p; p += 65536 * 2;
    u16* wf2 = (u16*)p; p += 65536 * 2;
    u16* qkvT = lnT;     // alias
    u16* xT   = qbuf;    // alias
    u16* y1   = Ktex;    // alias
    u16* y2T  = VtexT;   // alias

    dim3 blk(256);
    // weight converts
    f2bf_kernel<<<64,  blk, 0, stream>>>(qpw,  wq,  16384);
    f2bf_kernel<<<128, blk, 0, stream>>>(kvpw, wkv, 32768);
    f2bf_kernel<<<64,  blk, 0, stream>>>(opw,  wo,  16384);
    f2bf_kernel<<<64,  blk, 0, stream>>>(fc1w, wf1, 16384);
    f2bf_kernel<<<64,  blk, 0, stream>>>(fc2w, wf2, 16384);
    // projections
    ln_t_f32<<<dim3(128, 16), blk, 0, stream>>>(img, qnw, qnb, lnT);
    gemmT<0><<<dim3(32, 2, 16), blk, 0, stream>>>(wq, lnT, qbuf, (u16*)0, (float*)0, (const float*)0, (const float*)0);
    ln_t_f32<<<dim3(128, 16), blk, 0, stream>>>(tex, kvnw, kvnb, lnT);
    gemmT<1><<<dim3(32, 4, 16), blk, 0, stream>>>(wkv, lnT, Ktex, VtexT, (float*)0, (const float*)0, (const float*)0);
    ln_t_f32<<<dim3(128, 16), blk, 0, stream>>>(dep, kvnw, kvnb, lnT);
    gemmT<1><<<dim3(32, 4, 16), blk, 0, stream>>>(wkv, lnT, Kdep, VdepT, (float*)0, (const float*)0, (const float*)0);
    // attention
    rownorm_kernel<<<3 * 4096, blk, 0, stream>>>(qbuf, Ktex, Kdep, rq, rkt, rkd);
    scores_mfma<<<dim3(8, 64, 2), blk, 0, stream>>>(qbuf, Ktex, Kdep, Sp);
    softmax_kernel<<<dim3(64, 2), blk, 0, stream>>>(Sp, rq, rkt, rkd, ascale, Pp);
    pv_mfma<<<dim3(16, 64), blk, 0, stream>>>(Pp, VtexT, VdepT, qkvT);
    // x = img + o_proj(qkv) + b  (fp32 in d_out, bf16 xT in ws)
    gemmT<2><<<dim3(32, 2, 16), blk, 0, stream>>>(wo, qkvT, (u16*)0, xT, out, opb, img);
    // FFN
    ln_t_bf16T<<<1024, blk, 0, stream>>>(xT, fnw, fnb, lnT);
    gemmT<0><<<dim3(32, 2, 16), blk, 0, stream>>>(wf1, lnT, y1, (u16*)0, (float*)0, (const float*)0, (const float*)0);
    dwgelu_plane<<<dim3(32, 2, 16), blk, 0, stream>>>(y1, dww, y2T);
    gemmT<3><<<dim3(32, 2, 16), blk, 0, stream>>>(wf2, y2T, (u16*)0, (u16*)0, out, (const float*)0, out);
}

// Round 5
// 587.162 us; speedup vs baseline: 1.8255x; 1.0468x over previous
//
#include <hip/hip_runtime.h>

// Problem constants
#define BQ   16
#define CCH  256
#define HWP  4096   // H*W

typedef unsigned short u16;
typedef unsigned int   u32;
typedef __attribute__((ext_vector_type(8))) short bf16x8;   // 8 bf16 (4 VGPRs)
typedef __attribute__((ext_vector_type(4))) float f32x4;    // MFMA C/D

__device__ __forceinline__ float bf2f(u16 h) {
    union { u32 u; float f; } v; v.u = (u32)h << 16; return v.f;
}
__device__ __forceinline__ u16 f2bf_bits(float f) {
    u32 u = __float_as_uint(f);
    u32 r = (u + 0x7fffu + ((u >> 16) & 1u)) >> 16;   // RNE
    return (u16)r;
}
__device__ __forceinline__ u32 pack2(float a, float b) {
    return (u32)f2bf_bits(a) | ((u32)f2bf_bits(b) << 16);
}
// async global->LDS, 16B per lane; lds dest = wave-uniform base + lane*16
__device__ __forceinline__ void gload16(const u16* g, u16* l) {
    __builtin_amdgcn_global_load_lds(
        (const __attribute__((address_space(1))) void*)g,
        (__attribute__((address_space(3))) void*)l, 16, 0, 0);
}

// ---------------------------------------------------------------------------
// fp32 -> bf16 weight convert. n4 = count/4.
// ---------------------------------------------------------------------------
__global__ __launch_bounds__(256) void f2bf_kernel(
    const float* __restrict__ src, u16* __restrict__ dst, int n4)
{
    int i = blockIdx.x * 256 + threadIdx.x;
    if (i < n4) {
        float4 v = ((const float4*)src)[i];
        uint2 p; p.x = pack2(v.x, v.y); p.y = pack2(v.z, v.w);
        ((uint2*)dst)[i] = p;
    }
}

// ---------------------------------------------------------------------------
// LayerNorm over C + transpose: x fp32 [b][c][n] -> outT bf16 [b][n][c].
// LDS-staged tile, 32 n x 256 c per block. grid (128, 16), block 256.
// ---------------------------------------------------------------------------
__global__ __launch_bounds__(256) void ln_t_f32(
    const float* __restrict__ x, const float* __restrict__ wgt,
    const float* __restrict__ bias, u16* __restrict__ outT)
{
    __shared__ float tile[32 * 257];   // [n][c], stride 257 floats
    __shared__ float ps[256], pss[256];
    __shared__ float smu[32], srs[32];
    __shared__ float sw[CCH], sb[CCH];
    int tid = threadIdx.x;
    sw[tid] = wgt[tid]; sb[tid] = bias[tid];

    int nl = tid & 31, cg = tid >> 5;        // n-lane, channel group
    int b  = blockIdx.y;
    int n0 = blockIdx.x * 32;
    const float* xp = x + (size_t)b * CCH * HWP + n0 + nl;

    float s = 0.f, ss = 0.f;
    #pragma unroll
    for (int j = 0; j < 32; ++j) {
        int c = cg * 32 + j;
        float v = xp[(size_t)c * HWP];
        tile[nl * 257 + c] = v;
        s += v; ss += v * v;
    }
    ps[tid] = s; pss[tid] = ss;
    __syncthreads();

    if (tid < 32) {
        float t = 0.f, tt = 0.f;
        #pragma unroll
        for (int g = 0; g < 8; ++g) { t += ps[g * 32 + tid]; tt += pss[g * 32 + tid]; }
        float u = t * (1.0f / CCH);
        smu[tid] = u;
        srs[tid] = rsqrtf(tt * (1.0f / CCH) - u * u + 1e-6f);
    }
    __syncthreads();

    int c0 = (tid & 31) * 8, nb = tid >> 5;  // lanes 0..31 -> consecutive c
    #pragma unroll
    for (int r = 0; r < 4; ++r) {
        int n = r * 8 + nb;
        float u = smu[n], rr = srs[n];
        u16 tmp[8];
        #pragma unroll
        for (int j = 0; j < 8; ++j) {
            float v = tile[n * 257 + c0 + j];
            tmp[j] = f2bf_bits(sw[c0 + j] * (v - u) * rr + sb[c0 + j]);
        }
        *(uint4*)(outT + ((size_t)b * HWP + n0 + n) * CCH + c0) = *(uint4*)tmp;
    }
}

// ---------------------------------------------------------------------------
// Same, but input already bf16 T-layout [b][n][c] (used for LN of x).
// 4 threads/row, quad shuffle-reduce. grid 1024, block 256.
// ---------------------------------------------------------------------------
__global__ __launch_bounds__(256) void ln_t_bf16T(
    const u16* __restrict__ xT, const float* __restrict__ wgt,
    const float* __restrict__ bias, u16* __restrict__ outT)
{
    __shared__ float sw[CCH], sb[CCH];
    int tid = threadIdx.x;
    sw[tid] = wgt[tid]; sb[tid] = bias[tid];
    __syncthreads();
    int gid = blockIdx.x * 256 + tid;
    int ng = gid >> 2, q = gid & 3;          // 4 threads per (b,n) row
    int b = ng >> 12, n = ng & 4095;
    const u16* xp = xT + ((size_t)b * HWP + n) * CCH + q * 64;
    uint4 w4[8];
    float s = 0.f, ss = 0.f;
    #pragma unroll
    for (int k = 0; k < 8; ++k) {
        w4[k] = *(const uint4*)(xp + k * 8);
        const u16* ph = (const u16*)&w4[k];
        #pragma unroll
        for (int j = 0; j < 8; ++j) { float v = bf2f(ph[j]); s += v; ss += v * v; }
    }
    s  += __shfl_xor(s, 1);  s  += __shfl_xor(s, 2);
    ss += __shfl_xor(ss, 1); ss += __shfl_xor(ss, 2);
    float u = s * (1.0f / CCH);
    float r = rsqrtf(ss * (1.0f / CCH) - u * u + 1e-6f);
    u16* op = outT + ((size_t)b * HWP + n) * CCH + q * 64;
    #pragma unroll
    for (int k = 0; k < 8; ++k) {
        const u16* ph = (const u16*)&w4[k];
        int cb = q * 64 + k * 8;
        u16 tmp[8];
        #pragma unroll
        for (int j = 0; j < 8; ++j)
            tmp[j] = f2bf_bits(sw[cb + j] * (bf2f(ph[j]) - u) * r + sb[cb + j]);
        *(uint4*)(op + k * 8) = *(uint4*)tmp;
    }
}

// ---------------------------------------------------------------------------
// MFMA GEMM: Out[b][m][n] = sum_k Wb[m][k] * XT[b][n][k]   (K=256)
// v4: 512 threads / 8 waves (2m x 4n, wave tile 64x32) for occupancy;
// 128x128 tile, BK=32 double-buffered LDS via global_load_lds width-16
// (1 A + 1 B load/thread/step); LDS-transposed swizzled epilogues.
// MODE 0: orig bf16 out                      (q, fc1)
// MODE 1: m<256 -> orig bf16 K; m>=256 -> T bf16 V        (kv)
// MODE 2: +bias +resF(img); fp32 orig outF (d_out, scalar) AND T bf16 outB (xT)
// MODE 3: +resF; fp32 orig outF via 2-pass f32 tile (float4 ld/st)
// grid: (32, M/128, 16), block 512.
// ---------------------------------------------------------------------------
template<int MODE>
__global__ __launch_bounds__(512) void gemmT(
    const u16* __restrict__ Wb, const u16* __restrict__ XT,
    u16* __restrict__ outA, u16* __restrict__ outB,
    float* __restrict__ outF, const float* __restrict__ bias,
    const float* __restrict__ resF)
{
    // per buffer: A 128x32 (4096 u16) then B 128x32 (4096 u16) = 16 KB
    __shared__ __align__(16) u16 lds[2][8192];

    int tid = threadIdx.x;
    int w = tid >> 6, lane = tid & 63;
    int lr = lane & 15, quad = lane >> 4;
    int wm = w >> 2, wn = w & 3;          // wave tile: 64m x 32n
    int b   = blockIdx.z;
    int m0b = blockIdx.y * 128;
    int n0b = blockIdx.x * 128;
    int m0 = m0b + wm * 64;
    int n0 = n0b + wn * 32;

    // staging map: thread stages row tid/4, col (tid&3)*8 of the 128x32 tile
    int srow = tid >> 2;
    int scol = (tid & 3) * 8;
    const u16* gA = Wb + (size_t)(m0b + srow) * CCH + scol;
    const u16* gB = XT + ((size_t)b * HWP + n0b + srow) * CCH + scol;
    // wave-uniform LDS dest: wave w covers rows w*16.. -> offset w*512 u16
    u16* ldsA = (u16*)&lds[0][0]    + w * 512;
    u16* ldsB = (u16*)&lds[0][4096] + w * 512;

    f32x4 zz = {0.f, 0.f, 0.f, 0.f};
    f32x4 acc[4][2];
    #pragma unroll
    for (int i = 0; i < 4; ++i)
        #pragma unroll
        for (int j = 0; j < 2; ++j) acc[i][j] = zz;

    const u16* Ard = &lds[0][0] + (size_t)(wm * 64 + lr) * 32 + quad * 8;
    const u16* Brd = &lds[0][4096] + (size_t)(wn * 32 + lr) * 32 + quad * 8;

    // prologue: stage k0=0 into buf 0
    gload16(gA, ldsA);
    gload16(gB, ldsB);
    __syncthreads();

    #pragma unroll
    for (int t = 0; t < 8; ++t) {
        int cur = t & 1;
        if (t < 7) {      // stage next K-chunk into the other buffer
            int kk = (t + 1) * 32;
            gload16(gA + kk, ldsA + (cur ^ 1) * 8192);
            gload16(gB + kk, ldsB + (cur ^ 1) * 8192);
        }
        bf16x8 a[4], bb[2];
        #pragma unroll
        for (int mi = 0; mi < 4; ++mi) a[mi]  = *(const bf16x8*)(Ard + cur * 8192 + mi * 16 * 32);
        #pragma unroll
        for (int nj = 0; nj < 2; ++nj) bb[nj] = *(const bf16x8*)(Brd + cur * 8192 + nj * 16 * 32);
        #pragma unroll
        for (int mi = 0; mi < 4; ++mi)
            #pragma unroll
            for (int nj = 0; nj < 2; ++nj)
                acc[mi][nj] = __builtin_amdgcn_mfma_f32_16x16x32_bf16(a[mi], bb[nj], acc[mi][nj], 0, 0, 0);
        __syncthreads();   // drains staged loads (vmcnt) + protects buffer reuse
    }

    // ---- epilogues: LDS (now free) used as a transpose stage -------------
    char* tile = (char*)&lds[0][0];    // 32 KB

    if (MODE == 0 || (MODE == 1 && m0b < 256)) {
        // orig bf16 [b][m][n]: tile [128m][128n] u16, XOR-swizzled 16B chunks
        #pragma unroll
        for (int mi = 0; mi < 4; ++mi) {
            int mloc = wm * 64 + mi * 16 + quad * 4;
            #pragma unroll
            for (int nj = 0; nj < 2; ++nj) {
                int nl = wn * 32 + nj * 16 + lr;
                #pragma unroll
                for (int r = 0; r < 4; ++r) {
                    int m = mloc + r;
                    *(u16*)(tile + m * 256 + ((nl * 2) ^ ((m & 7) << 4))) =
                        f2bf_bits(acc[mi][nj][r]);
                }
            }
        }
        __syncthreads();
        #pragma unroll
        for (int p = 0; p < 4; ++p) {
            int cid = p * 512 + tid;
            int row = cid >> 4, ch = cid & 15;
            uint4 v = *(const uint4*)(tile + row * 256 + ((ch * 16) ^ ((row & 7) << 4)));
            *(uint4*)(outA + ((size_t)b * CCH + m0b + row) * HWP + n0b + ch * 8) = v;
        }
    } else if (MODE == 1) {
        // V-half -> T [b][n][c]: tile [128n][128m] u16, uint2 writes
        #pragma unroll
        for (int mi = 0; mi < 4; ++mi) {
            int mloc = wm * 64 + mi * 16 + quad * 4;
            #pragma unroll
            for (int nj = 0; nj < 2; ++nj) {
                int nl = wn * 32 + nj * 16 + lr;
                uint2 pp;
                pp.x = pack2(acc[mi][nj][0], acc[mi][nj][1]);
                pp.y = pack2(acc[mi][nj][2], acc[mi][nj][3]);
                *(uint2*)(tile + nl * 256 + ((mloc * 2) ^ ((nl & 7) << 4))) = pp;
            }
        }
        __syncthreads();
        int cbase = m0b - 256;
        #pragma unroll
        for (int p = 0; p < 4; ++p) {
            int cid = p * 512 + tid;
            int row = cid >> 4, ch = cid & 15;
            uint4 v = *(const uint4*)(tile + row * 256 + ((ch * 16) ^ ((row & 7) << 4)));
            *(uint4*)(outB + ((size_t)b * HWP + n0b + row) * CCH + cbase + ch * 8) = v;
        }
    } else if (MODE == 2) {
        // fp32 out scalar (needs bias+res anyway) + vectorized T bf16 (xT)
        #pragma unroll
        for (int mi = 0; mi < 4; ++mi) {
            int mbase = m0 + mi * 16 + quad * 4;
            int mloc  = wm * 64 + mi * 16 + quad * 4;
            #pragma unroll
            for (int nj = 0; nj < 2; ++nj) {
                int n  = n0 + nj * 16 + lr;
                int nl = wn * 32 + nj * 16 + lr;
                float v[4];
                size_t rb = ((size_t)b * CCH + mbase) * HWP + n;
                #pragma unroll
                for (int r = 0; r < 4; ++r) {
                    v[r] = acc[mi][nj][r] + bias[mbase + r] + resF[rb + (size_t)r * HWP];
                    outF[rb + (size_t)r * HWP] = v[r];
                }
                uint2 pp; pp.x = pack2(v[0], v[1]); pp.y = pack2(v[2], v[3]);
                *(uint2*)(tile + nl * 256 + ((mloc * 2) ^ ((nl & 7) << 4))) = pp;
            }
        }
        __syncthreads();
        #pragma unroll
        for (int p = 0; p < 4; ++p) {
            int cid = p * 512 + tid;
            int row = cid >> 4, ch = cid & 15;
            uint4 v = *(const uint4*)(tile + row * 256 + ((ch * 16) ^ ((row & 7) << 4)));
            *(uint4*)(outB + ((size_t)b * HWP + n0b + row) * CCH + m0b + ch * 8) = v;
        }
    } else {
        // MODE 3: fp32 out += resF, two n-half passes via [128m][64n] f32 tile
        #pragma unroll
        for (int pass = 0; pass < 2; ++pass) {
            if ((wn >> 1) == pass) {
                #pragma unroll
                for (int mi = 0; mi < 4; ++mi) {
                    #pragma unroll
                    for (int nj = 0; nj < 2; ++nj) {
                        int nin = (wn & 1) * 32 + nj * 16 + lr;
                        #pragma unroll
                        for (int r = 0; r < 4; ++r) {
                            int m = wm * 64 + mi * 16 + quad * 4 + r;
                            *(u32*)(tile + m * 256 + ((nin * 4) ^ ((m & 7) << 4))) =
                                __float_as_uint(acc[mi][nj][r]);
                        }
                    }
                }
            }
            __syncthreads();
            #pragma unroll
            for (int p = 0; p < 4; ++p) {
                int cid = p * 512 + tid;
                int row = cid >> 4, ch = cid & 15;
                float4 v = *(const float4*)(tile + row * 256 + ((ch * 16) ^ ((row & 7) << 4)));
                size_t g = ((size_t)b * CCH + m0b + row) * HWP + n0b + pass * 64 + ch * 4;
                float4 rr = *(const float4*)(resF + g);
                v.x += rr.x; v.y += rr.y; v.z += rr.z; v.w += rr.w;
                *(float4*)(outF + g) = v;
            }
            if (pass == 0) __syncthreads();
        }
    }
}

// ---------------------------------------------------------------------------
// Reciprocal L2 row norms over HW (vectorized uint4 loads).
// grid: 3*B*C blocks, block 256.
// ---------------------------------------------------------------------------
__global__ __launch_bounds__(256) void rownorm_kernel(
    const u16* __restrict__ q, const u16* __restrict__ Ktex, const u16* __restrict__ Kdep,
    float* __restrict__ rq, float* __restrict__ rkt, float* __restrict__ rkd)
{
    int tid = threadIdx.x;
    int idx = blockIdx.x;
    int which = idx >> 12;
    int bc = idx & 4095;
    const u16* row = (which == 0 ? q : which == 1 ? Ktex : Kdep) + (size_t)bc * HWP;
    float* out = (which == 0 ? rq : which == 1 ? rkt : rkd) + bc;
    float s = 0.f;
    const uint4* r4 = (const uint4*)row;
    #pragma unroll
    for (int it = 0; it < 2; ++it) {
        uint4 v = r4[tid * 2 + it];
        const u16* ph = (const u16*)&v;
        #pragma unroll
        for (int j = 0; j < 8; ++j) { float f = bf2f(ph[j]); s += f * f; }
    }
    #pragma unroll
    for (int off = 32; off > 0; off >>= 1) s += __shfl_down(s, off, 64);
    __shared__ float red[4];
    if ((tid & 63) == 0) red[tid >> 6] = s;
    __syncthreads();
    if (tid == 0) {
        float t = red[0] + red[1] + red[2] + red[3];
        out[0] = 1.0f / fmaxf(sqrtf(t), 1e-12f);
    }
}

// ---------------------------------------------------------------------------
// Scores partial (MFMA): Sp[which][bh][nc][c][d] = sum_{n in chunk} q[c][n]k[d][n]
// grid (8 nchunk, 64 bh, 2 which), block 256.
// ---------------------------------------------------------------------------
__global__ __launch_bounds__(256) void scores_mfma(
    const u16* __restrict__ q, const u16* __restrict__ Ktex, const u16* __restrict__ Kdep,
    float* __restrict__ Sp)
{
    int tid = threadIdx.x;
    int w = tid >> 6, lane = tid & 63;
    int lr = lane & 15, quad = lane >> 4;
    int nc = blockIdx.x, bh = blockIdx.y, which = blockIdx.z;
    int b = bh >> 2, h = bh & 3;
    const u16* Q = q + ((size_t)b * CCH + h * 64) * HWP;
    const u16* K = (which ? Kdep : Ktex) + ((size_t)b * CCH + h * 64) * HWP;

    f32x4 zz = {0.f, 0.f, 0.f, 0.f};
    f32x4 acc[4] = {zz, zz, zz, zz};
    const u16* Ab = Q + (size_t)(w * 16 + lr) * HWP + nc * 512 + quad * 8;
    const u16* Bb = K + (size_t)lr * HWP + nc * 512 + quad * 8;

    #pragma unroll 4
    for (int s = 0; s < 16; ++s) {
        int off = s * 32;
        bf16x8 a = *(const bf16x8*)(Ab + off);
        #pragma unroll
        for (int dj = 0; dj < 4; ++dj) {
            bf16x8 kb = *(const bf16x8*)(Bb + (size_t)dj * 16 * HWP + off);
            acc[dj] = __builtin_amdgcn_mfma_f32_16x16x32_bf16(a, kb, acc[dj], 0, 0, 0);
        }
    }
    float* out = Sp + (((size_t)(which * 64 + bh) * 8 + nc) * 4096);
    #pragma unroll
    for (int dj = 0; dj < 4; ++dj)
        #pragma unroll
        for (int r = 0; r < 4; ++r)
            out[(w * 16 + quad * 4 + r) * 64 + dj * 16 + lr] = acc[dj][r];
}

// ---------------------------------------------------------------------------
// Reduce partials + scale (rq*rk) + softmax + gate fold -> P bf16 [2][bh][c][d]
// grid (64 bh, 2 which), block 256.
// ---------------------------------------------------------------------------
__global__ __launch_bounds__(256) void softmax_kernel(
    const float* __restrict__ Sp, const float* __restrict__ rq,
    const float* __restrict__ rkt, const float* __restrict__ rkd,
    const float* __restrict__ ascale, u16* __restrict__ Pp)
{
    __shared__ float S[64][65];
    int tid = threadIdx.x;
    int bh = blockIdx.x, which = blockIdx.y;
    int b = bh >> 2, h = bh & 3;
    float g = 1.0f / (1.0f + expf(-ascale[h]));
    float gain = which ? (1.0f - g) : g;
    const float* base = Sp + ((size_t)(which * 64 + bh) * 8) * 4096;
    const float* rk  = (which ? rkd : rkt) + b * CCH + h * 64;
    const float* rqp = rq + b * CCH + h * 64;
    for (int i = tid; i < 4096; i += 256) {
        float s = 0.f;
        #pragma unroll
        for (int p = 0; p < 8; ++p) s += base[(size_t)p * 4096 + i];
        S[i >> 6][i & 63] = s * rqp[i >> 6] * rk[i & 63];
    }
    __syncthreads();
    if (tid < 64) {
        float mx = -1e30f;
        #pragma unroll 8
        for (int d = 0; d < 64; ++d) mx = fmaxf(mx, S[tid][d]);
        float sum = 0.f;
        #pragma unroll 8
        for (int d = 0; d < 64; ++d) { float e = expf(S[tid][d] - mx); S[tid][d] = e; sum += e; }
        float inv = gain / sum;
        u16* dst = Pp + ((size_t)(which * 64 + bh) * 64 + tid) * 64;
        #pragma unroll 8
        for (int d = 0; d < 64; ++d) dst[d] = f2bf_bits(S[tid][d] * inv);
    }
}

// ---------------------------------------------------------------------------
// PV (MFMA): qkvT[b][n][h*64+c] = sum_d P[c][d]*VT[n][d] over both sources.
// grid (16 nchunk, 64 bh), block 256.
// ---------------------------------------------------------------------------
__global__ __launch_bounds__(256) void pv_mfma(
    const u16* __restrict__ Pp, const u16* __restrict__ VtexT,
    const u16* __restrict__ VdepT, u16* __restrict__ qkvT)
{
    int tid = threadIdx.x;
    int w = tid >> 6, lane = tid & 63;
    int lr = lane & 15, quad = lane >> 4;
    int nc = blockIdx.x, bh = blockIdx.y;
    int b = bh >> 2, h = bh & 3;
    int n0 = nc * 256 + w * 64;

    f32x4 zz = {0.f, 0.f, 0.f, 0.f};
    f32x4 acc[4][4];
    #pragma unroll
    for (int i = 0; i < 4; ++i)
        #pragma unroll
        for (int j = 0; j < 4; ++j) acc[i][j] = zz;

    #pragma unroll
    for (int src = 0; src < 2; ++src) {
        const u16* P  = Pp + ((size_t)(src * 64 + bh) * 64) * 64;
        const u16* VT = (src ? VdepT : VtexT);
        const u16* Vb = VT + ((size_t)b * HWP + n0 + lr) * CCH + h * 64 + quad * 8;
        #pragma unroll
        for (int ks = 0; ks < 2; ++ks) {
            bf16x8 a[4], vv[4];
            #pragma unroll
            for (int ci = 0; ci < 4; ++ci)
                a[ci] = *(const bf16x8*)(P + (size_t)(ci * 16 + lr) * 64 + ks * 32 + quad * 8);
            #pragma unroll
            for (int nj = 0; nj < 4; ++nj)
                vv[nj] = *(const bf16x8*)(Vb + (size_t)nj * 16 * CCH + ks * 32);
            #pragma unroll
            for (int ci = 0; ci < 4; ++ci)
                #pragma unroll
                for (int nj = 0; nj < 4; ++nj)
                    acc[ci][nj] = __builtin_amdgcn_mfma_f32_16x16x32_bf16(a[ci], vv[nj], acc[ci][nj], 0, 0, 0);
        }
    }
    #pragma unroll
    for (int ci = 0; ci < 4; ++ci)
        #pragma unroll
        for (int nj = 0; nj < 4; ++nj) {
            int n = n0 + nj * 16 + lr;
            uint2 p;
            p.x = pack2(acc[ci][nj][0], acc[ci][nj][1]);
            p.y = pack2(acc[ci][nj][2], acc[ci][nj][3]);
            *(uint2*)(qkvT + ((size_t)b * HWP + n) * CCH + h * 64 + ci * 16 + quad * 4) = p;
        }
}

// ---------------------------------------------------------------------------
// Depthwise 3x3 + exact GELU, LDS-staged.
// grid (32, 2, 16), block 256.
// ---------------------------------------------------------------------------
__global__ __launch_bounds__(256) void dwgelu_plane(
    const u16* __restrict__ y1, const float* __restrict__ dww, u16* __restrict__ y2T)
{
    __shared__ u16 plane[8 * 34 * 72];   // 39168 B
    __shared__ float sdw[72];
    int tid = threadIdx.x;
    int cg = blockIdx.x, nh = blockIdx.y, b = blockIdx.z;
    if (tid < 72) sdw[tid] = dww[cg * 72 + tid];

    // fill: 8 ch x 34 rows x 8 uint4-chunks = 2176 chunks
    for (int idx = tid; idx < 2176; idx += 256) {
        int cl  = idx / 272;
        int rem = idx - cl * 272;
        int r   = rem >> 3;
        int cc  = (rem & 7) << 3;
        int gr  = nh * 32 + r - 1;
        uint4 v = make_uint4(0u, 0u, 0u, 0u);
        if ((unsigned)gr < 64u)
            v = *(const uint4*)(y1 + ((size_t)b * CCH + cg * 8 + cl) * HWP + gr * 64 + cc);
        *(uint4*)&plane[cl * 2448 + r * 72 + cc] = v;
    }
    __syncthreads();

    int nb  = tid * 8;           // 0..2047 within half-plane
    int lrow = nb >> 6;          // 0..31
    int ww0  = nb & 63;          // multiple of 8
    float acc[8][8];
    #pragma unroll
    for (int i = 0; i < 8; ++i)
        #pragma unroll
        for (int c = 0; c < 8; ++c) acc[i][c] = 0.f;

    #pragma unroll
    for (int cl = 0; cl < 8; ++cl) {
        const u16* pl = &plane[cl * 2448];
        #pragma unroll
        for (int dy = 0; dy < 3; ++dy) {
            int pr = lrow + dy;              // plane row (halo handles borders)
            const u16* rowp = pl + pr * 72 + ww0;
            uint4 m = *(const uint4*)rowp;
            const u16* mh = (const u16*)&m;
            float s[10];
            #pragma unroll
            for (int j = 0; j < 8; ++j) s[j + 1] = bf2f(mh[j]);
            s[0] = (ww0 > 0)  ? bf2f(rowp[-1]) : 0.f;
            s[9] = (ww0 < 56) ? bf2f(rowp[8])  : 0.f;
            float w0 = sdw[cl * 9 + dy * 3 + 0];
            float w1 = sdw[cl * 9 + dy * 3 + 1];
            float w2 = sdw[cl * 9 + dy * 3 + 2];
            #pragma unroll
            for (int i = 0; i < 8; ++i)
                acc[i][cl] += s[i] * w0 + s[i + 1] * w1 + s[i + 2] * w2;
        }
    }

    size_t outbase = ((size_t)b * HWP + nh * 2048 + nb) * CCH + cg * 8;
    #pragma unroll
    for (int i = 0; i < 8; ++i) {
        u16 tmp[8];
        #pragma unroll
        for (int c = 0; c < 8; ++c) {
            float a = acc[i][c];
            tmp[c] = f2bf_bits(0.5f * a * (1.0f + erff(a * 0.70710678118654752f)));
        }
        *(uint4*)(y2T + outbase + (size_t)i * CCH) = *(uint4*)tmp;
    }
}

// ---------------------------------------------------------------------------
// Workspace (~210 MB): lnT 32 | q 32 | Ktex 32 | VtexT 32 | Kdep 32 | VdepT 32
//   | Sp 16 | Pp 1 | norms 48K | wbf 784K.  Aliases: qkvT=lnT; xT=qbuf;
//   y1=Ktex; y2T=VtexT.  x lives in d_out (fp32).
// ---------------------------------------------------------------------------
extern "C" void kernel_launch(void* const* d_in, const int* in_sizes, int n_in,
                              void* d_out, int out_size, void* d_ws, size_t ws_size,
                              hipStream_t stream)
{
    const float* img    = (const float*)d_in[0];
    const float* tex    = (const float*)d_in[1];
    const float* dep    = (const float*)d_in[2];
    const float* qnw    = (const float*)d_in[3];
    const float* qnb    = (const float*)d_in[4];
    const float* kvnw   = (const float*)d_in[5];
    const float* kvnb   = (const float*)d_in[6];
    const float* ascale = (const float*)d_in[7];
    const float* qpw    = (const float*)d_in[8];
    const float* kvpw   = (const float*)d_in[9];
    const float* opw    = (const float*)d_in[10];
    const float* opb    = (const float*)d_in[11];
    const float* fnw    = (const float*)d_in[12];
    const float* fnb    = (const float*)d_in[13];
    const float* fc1w   = (const float*)d_in[14];
    const float* dww    = (const float*)d_in[15];
    const float* fc2w   = (const float*)d_in[16];
    float* out = (float*)d_out;

    const size_t TEN = (size_t)BQ * CCH * HWP;   // 16,777,216
    char* p = (char*)d_ws;
    u16* lnT   = (u16*)p; p += TEN * 2;
    u16* qbuf  = (u16*)p; p += TEN * 2;
    u16* Ktex  = (u16*)p; p += TEN * 2;
    u16* VtexT = (u16*)p; p += TEN * 2;
    u16* Kdep  = (u16*)p; p += TEN * 2;
    u16* VdepT = (u16*)p; p += TEN * 2;
    float* Sp  = (float*)p; p += (size_t)8 * 2 * 64 * 4096 * 4;   // 16 MB
    u16* Pp    = (u16*)p;  p += (size_t)2 * 64 * 64 * 64 * 2;     // 1 MB
    float* rq  = (float*)p; p += (size_t)BQ * CCH * 4;
    float* rkt = (float*)p; p += (size_t)BQ * CCH * 4;
    float* rkd = (float*)p; p += (size_t)BQ * CCH * 4;
    u16* wq  = (u16*)p; p += 65536 * 2;
    u16* wkv = (u16*)p; p += 131072 * 2;
    u16* wo  = (u16*)p; p += 65536 * 2;
    u16* wf1 = (u16*)p; p += 65536 * 2;
    u16* wf2 = (u16*)p; p += 65536 * 2;
    u16* qkvT = lnT;     // alias
    u16* xT   = qbuf;    // alias
    u16* y1   = Ktex;    // alias
    u16* y2T  = VtexT;   // alias

    dim3 blk(256);
    dim3 gblk(512);
    // weight converts
    f2bf_kernel<<<64,  blk, 0, stream>>>(qpw,  wq,  16384);
    f2bf_kernel<<<128, blk, 0, stream>>>(kvpw, wkv, 32768);
    f2bf_kernel<<<64,  blk, 0, stream>>>(opw,  wo,  16384);
    f2bf_kernel<<<64,  blk, 0, stream>>>(fc1w, wf1, 16384);
    f2bf_kernel<<<64,  blk, 0, stream>>>(fc2w, wf2, 16384);
    // projections
    ln_t_f32<<<dim3(128, 16), blk, 0, stream>>>(img, qnw, qnb, lnT);
    gemmT<0><<<dim3(32, 2, 16), gblk, 0, stream>>>(wq, lnT, qbuf, (u16*)0, (float*)0, (const float*)0, (const float*)0);
    ln_t_f32<<<dim3(128, 16), blk, 0, stream>>>(tex, kvnw, kvnb, lnT);
    gemmT<1><<<dim3(32, 4, 16), gblk, 0, stream>>>(wkv, lnT, Ktex, VtexT, (float*)0, (const float*)0, (const float*)0);
    ln_t_f32<<<dim3(128, 16), blk, 0, stream>>>(dep, kvnw, kvnb, lnT);
    gemmT<1><<<dim3(32, 4, 16), gblk, 0, stream>>>(wkv, lnT, Kdep, VdepT, (float*)0, (const float*)0, (const float*)0);
    // attention
    rownorm_kernel<<<3 * 4096, blk, 0, stream>>>(qbuf, Ktex, Kdep, rq, rkt, rkd);
    scores_mfma<<<dim3(8, 64, 2), blk, 0, stream>>>(qbuf, Ktex, Kdep, Sp);
    softmax_kernel<<<dim3(64, 2), blk, 0, stream>>>(Sp, rq, rkt, rkd, ascale, Pp);
    pv_mfma<<<dim3(16, 64), blk, 0, stream>>>(Pp, VtexT, VdepT, qkvT);
    // x = img + o_proj(qkv) + b  (fp32 in d_out, bf16 xT in ws)
    gemmT<2><<<dim3(32, 2, 16), gblk, 0, stream>>>(wo, qkvT, (u16*)0, xT, out, opb, img);
    // FFN
    ln_t_bf16T<<<1024, blk, 0, stream>>>(xT, fnw, fnb, lnT);
    gemmT<0><<<dim3(32, 2, 16), gblk, 0, stream>>>(wf1, lnT, y1, (u16*)0, (float*)0, (const float*)0, (const float*)0);
    dwgelu_plane<<<dim3(32, 2, 16), blk, 0, stream>>>(y1, dww, y2T);
    gemmT<3><<<dim3(32, 2, 16), gblk, 0, stream>>>(wf2, y2T, (u16*)0, (u16*)0, out, (const float*)0, out);
}